// Round 23
// baseline (216.162 us; speedup 1.0000x reference)
//
#include <hip/hip_runtime.h>
#include <hip/hip_bf16.h>
#include <math.h>

// Problem dims (fixed by reference)
#define BB 4
#define SS 2048
#define EE 256
#define HH 8
#define DD 32
#define LL 2
#define NI 1024
#define NROWS (BB*SS)   // 8192
#define NRL   (BB*HH*SS) // 65536 flat (b,h,s) rows

typedef float f32x4 __attribute__((ext_vector_type(4)));
typedef short s16x8 __attribute__((ext_vector_type(8)));
typedef __bf16 bf16x8 __attribute__((ext_vector_type(8)));
typedef unsigned short ushort_t;

// 1/sqrt(32) * log2(e): QK scores land in log2 domain -> exp2f everywhere.
#define QSCALE 0.2550352699458294f

__device__ __forceinline__ unsigned short f2bf(float f) {
    return __builtin_bit_cast(unsigned short, (__bf16)f);   // native RNE cvt
}
__device__ __forceinline__ float bf2f(unsigned short s) {
    return __uint_as_float((unsigned)s << 16);
}
__device__ __forceinline__ f32x4 mfma16x16x32(s16x8 a, s16x8 b, f32x4 c) {
    return __builtin_amdgcn_mfma_f32_16x16x32_bf16(
        __builtin_bit_cast(bf16x8, a), __builtin_bit_cast(bf16x8, b), c, 0, 0, 0);
}

// ---------------------------------------------------------------------------
// Fused embedding + LN1(layer 0): h = wte[id]+wpe; x_bf = LN(h,g,b).
__global__ __launch_bounds__(256) void embed_ln_kernel(
    const int* __restrict__ ids, const float* __restrict__ wte,
    const float* __restrict__ wpe, const float* __restrict__ g,
    const float* __restrict__ b, float* __restrict__ h, ushort_t* __restrict__ x)
{
    int row  = blockIdx.x * 4 + (threadIdx.x >> 6);
    int s    = row & (SS - 1);
    int lane = threadIdx.x & 63;
    int id   = ids[row];
    float4 a = *(const float4*)(wte + (size_t)id * EE + lane * 4);
    float4 p = *(const float4*)(wpe + (size_t)s  * EE + lane * 4);
    float4 v = { a.x + p.x, a.y + p.y, a.z + p.z, a.w + p.w };
    *(float4*)(h + (size_t)row * EE + lane * 4) = v;
    float sm  = v.x + v.y + v.z + v.w;
    float ss2 = v.x*v.x + v.y*v.y + v.z*v.z + v.w*v.w;
    #pragma unroll
    for (int off = 32; off; off >>= 1) {
        sm  += __shfl_xor(sm,  off);
        ss2 += __shfl_xor(ss2, off);
    }
    float mu  = sm * (1.f / EE);
    float var = ss2 * (1.f / EE) - mu * mu;
    float rs  = rsqrtf(var + 1e-5f);
    float4 gv = *(const float4*)(g + lane * 4);
    float4 bv = *(const float4*)(b + lane * 4);
    ushort4 w = { f2bf((v.x - mu) * rs * gv.x + bv.x),
                  f2bf((v.y - mu) * rs * gv.y + bv.y),
                  f2bf((v.z - mu) * rs * gv.z + bv.z),
                  f2bf((v.w - mu) * rs * gv.w + bv.w) };
    *(ushort4*)(x + (size_t)row * EE + lane * 4) = w;
}

// ---------------------------------------------------------------------------
// LayerNorm over E=256; 4 rows per 256-thread block (wave per row).
template<bool OUTBF>
__global__ __launch_bounds__(256) void ln_kernel(
    const float* __restrict__ in, const float* __restrict__ g,
    const float* __restrict__ b, void* __restrict__ out)
{
    int row  = blockIdx.x * 4 + (threadIdx.x >> 6);
    int lane = threadIdx.x & 63;
    float4 v = *(const float4*)(in + (size_t)row * EE + lane * 4);
    float s  = v.x + v.y + v.z + v.w;
    float ss = v.x*v.x + v.y*v.y + v.z*v.z + v.w*v.w;
    #pragma unroll
    for (int off = 32; off; off >>= 1) {
        s  += __shfl_xor(s,  off);
        ss += __shfl_xor(ss, off);
    }
    float mu  = s * (1.f / EE);
    float var = ss * (1.f / EE) - mu * mu;
    float rs  = rsqrtf(var + 1e-5f);
    float4 gv = *(const float4*)(g + lane * 4);
    float4 bv = *(const float4*)(b + lane * 4);
    float4 o;
    o.x = (v.x - mu) * rs * gv.x + bv.x;
    o.y = (v.y - mu) * rs * gv.y + bv.y;
    o.z = (v.z - mu) * rs * gv.z + bv.z;
    o.w = (v.w - mu) * rs * gv.w + bv.w;
    if (OUTBF) {
        ushort4 w = { f2bf(o.x), f2bf(o.y), f2bf(o.z), f2bf(o.w) };
        *(ushort4*)((ushort_t*)out + (size_t)row * EE + lane * 4) = w;
    } else {
        *(float4*)((float*)out + (size_t)row * EE + lane * 4) = o;
    }
}

// ---------------------------------------------------------------------------
// Merged weight transpose+convert: all 8 jobs (4 weights x 2 layers), one
// launch. Grid (768, 2): t<192 qkv | <256 proj | <512 fc1 | else fc2.
__global__ __launch_bounds__(256) void wconv_all(
    const float* __restrict__ qkv_w, const float* __restrict__ proj_w,
    const float* __restrict__ fc1_w, const float* __restrict__ fc2_w,
    ushort_t* __restrict__ wq_t, ushort_t* __restrict__ wp_t,
    ushort_t* __restrict__ w1_t, ushort_t* __restrict__ w2_t)
{
    __shared__ float t_[32][33];
    int l = blockIdx.y, t = blockIdx.x;
    const float* W; ushort_t* Wt; int K, N, n0, k0;
    if (t < 192)      { W = qkv_w  + (size_t)l*EE*3*EE; Wt = wq_t + (size_t)l*3*EE*EE;
                        K = EE; N = 3*EE; int u = t;       n0 = (u % 24) * 32; k0 = (u / 24) * 32; }
    else if (t < 256) { W = proj_w + (size_t)l*EE*EE;   Wt = wp_t + (size_t)l*EE*EE;
                        K = EE; N = EE;   int u = t - 192; n0 = (u % 8)  * 32; k0 = (u / 8)  * 32; }
    else if (t < 512) { W = fc1_w  + (size_t)l*EE*NI;   Wt = w1_t + (size_t)l*EE*NI;
                        K = EE; N = NI;   int u = t - 256; n0 = (u % 32) * 32; k0 = (u / 32) * 32; }
    else              { W = fc2_w  + (size_t)l*NI*EE;   Wt = w2_t + (size_t)l*NI*EE;
                        K = NI; N = EE;   int u = t - 512; n0 = (u % 8)  * 32; k0 = (u / 8)  * 32; }
    int tx = threadIdx.x & 31, ty = threadIdx.x >> 5;
    #pragma unroll
    for (int i = 0; i < 4; ++i) {
        int k = ty + i * 8;
        t_[k][tx] = W[(size_t)(k0 + k) * N + n0 + tx];
    }
    __syncthreads();
    #pragma unroll
    for (int i = 0; i < 4; ++i) {
        int n = ty + i * 8;
        Wt[(size_t)(n0 + n) * K + k0 + tx] = f2bf(t_[tx][n]);
    }
}

// ---------------------------------------------------------------------------
// bf16 MFMA GEMM (r22 structure: 2-stage reg pipeline, lgkm-only barriers,
// XCD remap, hw-exp2 GELU, optional fused split-K attention merge on A).
template<int MI, bool OUT_BF, bool GELU_ACT, bool RES, bool QSC, bool MERGEA>
__global__ __launch_bounds__(256) void gemm_bf(
    const ushort_t* __restrict__ A, const ushort_t* __restrict__ Bt,
    const float* __restrict__ bias, const float* __restrict__ res,
    void* __restrict__ C, const float* __restrict__ lp,
    int M, int N, int K)
{
    __shared__ __align__(16) ushort_t As[MI*64][40];
    __shared__ __align__(16) ushort_t Bs[64][40];
    int tid = threadIdx.x;
    int wid = tid >> 6, lane = tid & 63;
    int h = lane >> 4, c = lane & 15;

    // XCD-grouped remap (all our grids have nwg % 8 == 0)
    int nbx = gridDim.x;
    int nwg = nbx * gridDim.y;
    int flat = blockIdx.y * nbx + blockIdx.x;
    int v = (flat & 7) * (nwg >> 3) + (flat >> 3);
    int bx = v % nbx, by = v / nbx;

    f32x4 acc[MI][4] = {};

    int arow = tid >> 2, ac = tid & 3;
    const ushort_t* Ap = A  + (size_t)(by * (MI*64) + arow) * K + ac * 8;
    const ushort_t* Bp = Bt + (size_t)(bx * 64     + arow) * K + ac * 8;

    // MERGEA per-thread row state (MI==1 for merge path)
    int mb = 0, msr = 0, mnp = 0, colbase = ac * 8;
    if (MERGEA) {
        int mrow = by * 64 + arow;
        mb  = mrow >> 11;            // / SS
        msr = mrow & (SS - 1);
        mnp = ((msr >> 6) >> 3) + 1; // 1..4 pieces
    }

    // two register stages
    s16x8 a0[MI], a1[MI], b0, b1;
    s16x8 mo0[4], mo1[4];
    float ml0[4], ml1[4];

    #define M_ISSUE(kk, MO, ML) do {                                          \
        int col = (kk) + colbase;                                             \
        int hh2 = col >> 5, d0 = col & 31;                                    \
        size_t rl = ((size_t)(mb * HH + hh2)) * SS + msr;                     \
        _Pragma("unroll")                                                     \
        for (int i_ = 0; i_ < 4; ++i_) {                                      \
            if (i_ < mnp) {                                                   \
                MO[i_] = *(const s16x8*)(A + ((size_t)i_ * NRL + rl) * DD + d0); \
                ML[i_] = lp[(size_t)i_ * NRL + rl];                           \
            } else { MO[i_] = (s16x8){0,0,0,0,0,0,0,0}; ML[i_] = 0.f; }       \
        }                                                                     \
    } while (0)

    #define M_COMBINE(MO, ML, OUTV) do {                                      \
        float L_ = ML[0] + ML[1] + ML[2] + ML[3];                             \
        float inv_ = __builtin_amdgcn_rcpf(L_);                               \
        _Pragma("unroll")                                                     \
        for (int e_ = 0; e_ < 8; ++e_) {                                      \
            float s_ = bf2f((ushort_t)MO[0][e_]) + bf2f((ushort_t)MO[1][e_])  \
                     + bf2f((ushort_t)MO[2][e_]) + bf2f((ushort_t)MO[3][e_]); \
            OUTV[e_] = (short)f2bf(s_ * inv_);                                \
        }                                                                     \
    } while (0)

    // prologue: two stages in flight
    if (MERGEA) { M_ISSUE(0, mo0, ml0); M_ISSUE(32, mo1, ml1); }
    else {
        #pragma unroll
        for (int i = 0; i < MI; ++i) a0[i] = *(const s16x8*)(Ap + (size_t)i * 64 * K);
        #pragma unroll
        for (int i = 0; i < MI; ++i) a1[i] = *(const s16x8*)(Ap + (size_t)i * 64 * K + 32);
    }
    b0 = *(const s16x8*)(Bp);
    b1 = *(const s16x8*)(Bp + 32);

    for (int k0 = 0; k0 < K; k0 += 64) {
        // ---- half A: consume stage0 (k0), prefetch k0+64 ----
        asm volatile("s_waitcnt lgkmcnt(0)" ::: "memory");
        __builtin_amdgcn_s_barrier();      // WAR: prev half's LDS reads done
        asm volatile("" ::: "memory");
        if (MERGEA) {
            s16x8 mv; M_COMBINE(mo0, ml0, mv);
            *(s16x8*)&As[arow][ac * 8] = mv;
        } else {
            #pragma unroll
            for (int i = 0; i < MI; ++i)
                *(s16x8*)&As[i * 64 + arow][ac * 8] = a0[i];
        }
        *(s16x8*)&Bs[arow][ac * 8] = b0;
        if (k0 + 64 < K) {
            if (MERGEA) M_ISSUE(k0 + 64, mo0, ml0);
            else {
                #pragma unroll
                for (int i = 0; i < MI; ++i)
                    a0[i] = *(const s16x8*)(Ap + (size_t)i * 64 * K + k0 + 64);
            }
            b0 = *(const s16x8*)(Bp + k0 + 64);
        }
        asm volatile("s_waitcnt lgkmcnt(0)" ::: "memory");
        __builtin_amdgcn_s_barrier();      // RAW: tile visible
        asm volatile("" ::: "memory");
        {
            s16x8 af[MI], bfr[4];
            #pragma unroll
            for (int i = 0; i < MI; ++i)
                af[i] = *(const s16x8*)&As[wid * (MI*16) + i * 16 + c][h * 8];
            #pragma unroll
            for (int j = 0; j < 4; ++j)
                bfr[j] = *(const s16x8*)&Bs[j * 16 + c][h * 8];
            #pragma unroll
            for (int i = 0; i < MI; ++i)
                #pragma unroll
                for (int j = 0; j < 4; ++j)
                    acc[i][j] = mfma16x16x32(af[i], bfr[j], acc[i][j]);
        }
        // ---- half B: consume stage1 (k0+32), prefetch k0+96 ----
        asm volatile("s_waitcnt lgkmcnt(0)" ::: "memory");
        __builtin_amdgcn_s_barrier();
        asm volatile("" ::: "memory");
        if (MERGEA) {
            s16x8 mv; M_COMBINE(mo1, ml1, mv);
            *(s16x8*)&As[arow][ac * 8] = mv;
        } else {
            #pragma unroll
            for (int i = 0; i < MI; ++i)
                *(s16x8*)&As[i * 64 + arow][ac * 8] = a1[i];
        }
        *(s16x8*)&Bs[arow][ac * 8] = b1;
        if (k0 + 96 < K) {
            if (MERGEA) M_ISSUE(k0 + 96, mo1, ml1);
            else {
                #pragma unroll
                for (int i = 0; i < MI; ++i)
                    a1[i] = *(const s16x8*)(Ap + (size_t)i * 64 * K + k0 + 96);
            }
            b1 = *(const s16x8*)(Bp + k0 + 96);
        }
        asm volatile("s_waitcnt lgkmcnt(0)" ::: "memory");
        __builtin_amdgcn_s_barrier();
        asm volatile("" ::: "memory");
        {
            s16x8 af[MI], bfr[4];
            #pragma unroll
            for (int i = 0; i < MI; ++i)
                af[i] = *(const s16x8*)&As[wid * (MI*16) + i * 16 + c][h * 8];
            #pragma unroll
            for (int j = 0; j < 4; ++j)
                bfr[j] = *(const s16x8*)&Bs[j * 16 + c][h * 8];
            #pragma unroll
            for (int i = 0; i < MI; ++i)
                #pragma unroll
                for (int j = 0; j < 4; ++j)
                    acc[i][j] = mfma16x16x32(af[i], bfr[j], acc[i][j]);
        }
    }
    #undef M_ISSUE
    #undef M_COMBINE

    float bj[4];
    #pragma unroll
    for (int j = 0; j < 4; ++j) bj[j] = bias[bx * 64 + j * 16 + c];
    #pragma unroll
    for (int i = 0; i < MI; ++i) {
        #pragma unroll
        for (int r = 0; r < 4; ++r) {
            int row = by * (MI*64) + wid * (MI*16) + i * 16 + h * 4 + r;
            #pragma unroll
            for (int j = 0; j < 4; ++j) {
                int col = bx * 64 + j * 16 + c;
                float v2 = acc[i][j][r] + bj[j];
                if (QSC && col < EE) v2 *= QSCALE;
                if (RES) v2 += res[(size_t)row * N + col];
                if (GELU_ACT) {
                    float u = 0.7978845608028654f * (v2 + 0.044715f * v2 * v2 * v2);
                    float t = exp2f(2.8853900817779268f * u);   // e^(2u)
                    v2 = v2 - v2 * __builtin_amdgcn_rcpf(t + 1.f); // v*t/(t+1)
                }
                if (OUT_BF) ((ushort_t*)C)[(size_t)row * N + col] = f2bf(v2);
                else        ((float*)C)[(size_t)row * N + col]    = v2;
            }
        }
    }
}

// ---------------------------------------------------------------------------
// Split-K causal flash attention (partial pass). PTILES=8, 80 pieces/(b,h).
// ROUND-23 (K direct-from-global): the QK B-operand fragment for lane (c,h),
// group g is K[key=g*16+c][dims h*8..+7] = a contiguous 16B global load.
// Load the 4 K-frags per lane directly (prefetched one tile ahead, issued
// right after their last use -> a full tile of latency cover). Removes the
// Ks LDS round-trip (1 b128 write + 4 b128 reads/lane/tile) and decouples
// QK from the barrier. LDS keeps only Vt (transpose) + per-wave Ps. Both
// barriers are lgkm-only (per-wave ds-reads done pre-barrier; vmcnt waits
// are compiler-placed at first use, per-wave). Cost: 4x redundant K reads
// (L2-resident, ~overlappable).
#define QB 64
#define VSTR 88
#define PSTR 72
#define PTILES 8
__global__ __launch_bounds__(256) void attn_kernel(
    const ushort_t* __restrict__ qkv, ushort_t* __restrict__ o_part,
    float* __restrict__ l_part)
{
    __shared__ __align__(16) ushort_t Vt[DD][VSTR];
    __shared__ __align__(16) ushort_t Ps[4][16][PSTR];

    int tid  = threadIdx.x;
    int p    = 79 - blockIdx.x;              // heavy (high qt) first
    int qt, ks;
    if (p < 8)       { qt = p;                 ks = 0; }
    else if (p < 24) { qt = 8  + ((p-8)  >> 1); ks = (p-8)  & 1; }
    else if (p < 48) { qt = 16 + (p-24) / 3;    ks = (p-24) % 3; }
    else             { qt = 24 + ((p-48) >> 2); ks = (p-48) & 3; }
    int hh   = blockIdx.y, b = blockIdx.z;
    int wid  = tid >> 6, lane = tid & 63;
    int h    = lane >> 4, c = lane & 15;

    int qfrow = qt * QB + wid * 16 + c;
    s16x8 qfrag = *(const s16x8*)(qkv + ((size_t)(b * SS + qfrow)) * (3*EE)
                                  + hh * DD + h * 8);

    s16x8 onesf = { (short)0x3F80, (short)0x3F80, (short)0x3F80, (short)0x3F80,
                    (short)0x3F80, (short)0x3F80, (short)0x3F80, (short)0x3F80 };

    f32x4 o0 = {0.f,0.f,0.f,0.f}, o1 = {0.f,0.f,0.f,0.f}, o2 = {0.f,0.f,0.f,0.f};

    int srow = tid >> 2, scq = tid & 3;
    int t0 = ks * PTILES;
    int t1 = min(t0 + PTILES, qt + 1);

    // per-lane K fragment pointers: row (g*16+c), dims h*8..+7 of this head
    const ushort_t* kfp = qkv + ((size_t)(b * SS + c)) * (3*EE) + hh * DD + EE + h * 8;
    const size_t KROW = (size_t)(3*EE);

    // prologue: K frags + V rows for tile t0
    s16x8 kf[4], vreg;
    {
        size_t base = (size_t)(t0 * QB) * KROW;
        #pragma unroll
        for (int g = 0; g < 4; ++g)
            kf[g] = *(const s16x8*)(kfp + base + (size_t)(g * 16) * KROW);
        const ushort_t* vb = qkv + ((size_t)(b * SS + t0 * QB)) * KROW + hh * DD + 2*EE;
        vreg = *(const s16x8*)(vb + (size_t)srow * KROW + scq * 8);
    }

    for (int kt = t0; kt < t1; ++kt) {
        int k0 = kt * QB;

        // WAR barrier (lgkm-only): prev tile's Vt/Ps reads done per-wave
        asm volatile("s_waitcnt lgkmcnt(0)" ::: "memory");
        __builtin_amdgcn_s_barrier();
        asm volatile("" ::: "memory");

        // stage V (transposed, swizzled); vmcnt wait hits vreg only
        {
            int d0 = scq * 8;
            int colw = srow ^ (scq << 4);          // XOR swizzle
            #pragma unroll
            for (int j = 0; j < 8; ++j) Vt[d0 + j][colw] = (ushort_t)vreg[j];
        }
        if (kt + 1 < t1) {
            const ushort_t* vb2 = qkv + ((size_t)(b * SS + (kt+1) * QB)) * KROW
                                  + hh * DD + 2*EE;
            vreg = *(const s16x8*)(vb2 + (size_t)srow * KROW + scq * 8);
        }

        // RAW barrier (lgkm-only): Vt visible
        asm volatile("s_waitcnt lgkmcnt(0)" ::: "memory");
        __builtin_amdgcn_s_barrier();
        asm volatile("" ::: "memory");

        __builtin_amdgcn_s_setprio(1);

        // QK (swapped, K from registers): lane holds S[q=c][key=g*16+h*4+r]
        f32x4 sg[4];
        #pragma unroll
        for (int g = 0; g < 4; ++g) {
            f32x4 z = {0.f,0.f,0.f,0.f};
            sg[g] = mfma16x16x32(kf[g], qfrag, z);
        }

        // prefetch next tile's K frags (after last kf use; full-tile cover)
        if (kt + 1 < t1) {
            size_t base = (size_t)((kt + 1) * QB) * KROW;
            #pragma unroll
            for (int g = 0; g < 4; ++g)
                kf[g] = *(const s16x8*)(kfp + base + (size_t)(g * 16) * KROW);
        }

        if (kt == qt) {                       // diagonal tile: masked path
            int klim = qfrow - k0;
            #pragma unroll
            for (int g = 0; g < 4; ++g) {
                ushort4 pk;
                #pragma unroll
                for (int r = 0; r < 4; ++r) {
                    float x = sg[g][r];
                    if (g * 16 + h * 4 + r > klim) x = -INFINITY;
                    ((ushort_t*)&pk)[r] = f2bf(exp2f(x));
                }
                *(ushort4*)&Ps[wid][c][g * 16 + h * 4] = pk;
            }
        } else {                              // interior tile: no masking
            #pragma unroll
            for (int g = 0; g < 4; ++g) {
                ushort4 pk;
                #pragma unroll
                for (int r = 0; r < 4; ++r)
                    ((ushort_t*)&pk)[r] = f2bf(exp2f(sg[g][r]));
                *(ushort4*)&Ps[wid][c][g * 16 + h * 4] = pk;
            }
        }

        #pragma unroll
        for (int kc = 0; kc < 2; ++kc) {
            int kbase = kc * 32 + h * 8;
            s16x8 pf = *(const s16x8*)&Ps[wid][c][kbase];
            s16x8 v0 = *(const s16x8*)&Vt[c]     [kbase ^ ((c >> 3) << 4)];
            s16x8 v1 = *(const s16x8*)&Vt[16 + c][kbase ^ (((16 + c) >> 3) << 4)];
            o0 = mfma16x16x32(pf, v0, o0);
            o1 = mfma16x16x32(pf, v1, o1);
            o2 = mfma16x16x32(pf, onesf, o2);   // row sums -> l
        }

        __builtin_amdgcn_s_setprio(0);
    }

    // write partials for ALL rows (merge fused into proj GEMM)
    size_t rbase = (size_t)(b * HH + hh) * SS;
    #pragma unroll
    for (int r = 0; r < 4; ++r) {
        int qrow = qt * QB + wid * 16 + h * 4 + r;
        size_t rl = rbase + qrow;
        ushort_t* op = o_part + ((size_t)ks * NRL + rl) * DD;
        op[c]      = f2bf(o0[r]);
        op[16 + c] = f2bf(o1[r]);
        if (c == 0) l_part[(size_t)ks * NRL + rl] = o2[r];
    }
}

// ---------------------------------------------------------------------------
extern "C" void kernel_launch(void* const* d_in, const int* in_sizes, int n_in,
                              void* d_out, int out_size, void* d_ws, size_t ws_size,
                              hipStream_t stream)
{
    const int*   ids    = (const int*)  d_in[0];
    const float* wte    = (const float*)d_in[1];
    const float* wpe    = (const float*)d_in[2];
    const float* ln1_g  = (const float*)d_in[3];
    const float* ln1_b  = (const float*)d_in[4];
    const float* qkv_w  = (const float*)d_in[5];
    const float* qkv_b  = (const float*)d_in[6];
    const float* proj_w = (const float*)d_in[7];
    const float* proj_b = (const float*)d_in[8];
    const float* ln2_g  = (const float*)d_in[9];
    const float* ln2_b  = (const float*)d_in[10];
    const float* fc1_w  = (const float*)d_in[11];
    const float* fc1_b  = (const float*)d_in[12];
    const float* fc2_w  = (const float*)d_in[13];
    const float* fc2_b  = (const float*)d_in[14];
    const float* lnf_g  = (const float*)d_in[15];
    const float* lnf_b  = (const float*)d_in[16];

    float*    h        = (float*)d_ws;                         // 8192*256 f32
    ushort_t* x_bf     = (ushort_t*)(h + (size_t)NROWS*EE);    // 8192*256
    ushort_t* qkv_bf   = x_bf   + (size_t)NROWS*EE;            // 8192*768
    ushort_t* attno_bf = qkv_bf + (size_t)NROWS*3*EE;          // 8192*256 (spare)
    ushort_t* m1_bf    = attno_bf + (size_t)NROWS*EE;          // 8192*1024
    ushort_t* wq_t     = m1_bf  + (size_t)NROWS*NI;            // [2][768][256]
    ushort_t* wp_t     = wq_t   + (size_t)2*3*EE*EE;           // [2][256][256]
    ushort_t* w1_t     = wp_t   + (size_t)2*EE*EE;             // [2][1024][256]
    ushort_t* w2_t     = w1_t   + (size_t)2*EE*NI;             // [2][256][1024]

    // split-K scratch overlays (regions dead during attention + proj):
    ushort_t* o_part   = m1_bf;              // 4*65536*32*2B = 16.78MB == m1 region
    float*    l_part   = (float*)x_bf;       // 4*65536*4B    = 1.05MB  <  x region

    wconv_all<<<dim3(768, LL), 256, 0, stream>>>(
        qkv_w, proj_w, fc1_w, fc2_w, wq_t, wp_t, w1_t, w2_t);

    embed_ln_kernel<<<NROWS/4, 256, 0, stream>>>(ids, wte, wpe, ln1_g, ln1_b, h, x_bf);

    for (int l = 0; l < LL; ++l) {
        if (l > 0)
            ln_kernel<true><<<NROWS/4, 256, 0, stream>>>(h, ln1_g + l*EE, ln1_b + l*EE, x_bf);
        gemm_bf<2,true,false,false,true,false><<<dim3(3*EE/64, NROWS/128), 256, 0, stream>>>(
            x_bf, wq_t + (size_t)l*3*EE*EE, qkv_b + (size_t)l*3*EE, nullptr,
            qkv_bf, nullptr, NROWS, 3*EE, EE);
        attn_kernel<<<dim3(80, HH, BB), 256, 0, stream>>>(qkv_bf, o_part, l_part);
        // proj GEMM with fused split-K merge (A = o_part + l_part)
        gemm_bf<1,false,false,true,false,true><<<dim3(EE/64, NROWS/64), 256, 0, stream>>>(
            o_part, wp_t + (size_t)l*EE*EE, proj_b + (size_t)l*EE, h,
            h, l_part, NROWS, EE, EE);
        ln_kernel<true><<<NROWS/4, 256, 0, stream>>>(h, ln2_g + l*EE, ln2_b + l*EE, x_bf);
        gemm_bf<2,true,true,false,false,false><<<dim3(NI/64, NROWS/128), 256, 0, stream>>>(
            x_bf, w1_t + (size_t)l*EE*NI, fc1_b + (size_t)l*NI, nullptr,
            m1_bf, nullptr, NROWS, NI, EE);
        gemm_bf<1,false,false,true,false,false><<<dim3(EE/64, NROWS/64), 256, 0, stream>>>(
            m1_bf, w2_t + (size_t)l*NI*EE, fc2_b + (size_t)l*EE, h,
            h, nullptr, NROWS, EE, NI);
    }

    ln_kernel<false><<<NROWS/4, 256, 0, stream>>>(h, lnf_g, lnf_b, (float*)d_out);
}

// Round 24
// 182.769 us; speedup vs baseline: 1.1827x; 1.1827x over previous
//
#include <hip/hip_runtime.h>
#include <hip/hip_bf16.h>
#include <math.h>

// Problem dims (fixed by reference)
#define BB 4
#define SS 2048
#define EE 256
#define HH 8
#define DD 32
#define LL 2
#define NI 1024
#define NROWS (BB*SS)   // 8192
#define NRL   (BB*HH*SS) // 65536 flat (b,h,s) rows

typedef float f32x4 __attribute__((ext_vector_type(4)));
typedef short s16x8 __attribute__((ext_vector_type(8)));
typedef __bf16 bf16x8 __attribute__((ext_vector_type(8)));
typedef unsigned short ushort_t;

// 1/sqrt(32) * log2(e): QK scores land in log2 domain -> exp2f everywhere.
#define QSCALE 0.2550352699458294f

__device__ __forceinline__ unsigned short f2bf(float f) {
    return __builtin_bit_cast(unsigned short, (__bf16)f);   // native RNE cvt
}
__device__ __forceinline__ float bf2f(unsigned short s) {
    return __uint_as_float((unsigned)s << 16);
}
__device__ __forceinline__ f32x4 mfma16x16x32(s16x8 a, s16x8 b, f32x4 c) {
    return __builtin_amdgcn_mfma_f32_16x16x32_bf16(
        __builtin_bit_cast(bf16x8, a), __builtin_bit_cast(bf16x8, b), c, 0, 0, 0);
}

// ---------------------------------------------------------------------------
// Fused embedding + LN1(layer 0): h = wte[id]+wpe; x_bf = LN(h,g,b).
__global__ __launch_bounds__(256) void embed_ln_kernel(
    const int* __restrict__ ids, const float* __restrict__ wte,
    const float* __restrict__ wpe, const float* __restrict__ g,
    const float* __restrict__ b, float* __restrict__ h, ushort_t* __restrict__ x)
{
    int row  = blockIdx.x * 4 + (threadIdx.x >> 6);
    int s    = row & (SS - 1);
    int lane = threadIdx.x & 63;
    int id   = ids[row];
    float4 a = *(const float4*)(wte + (size_t)id * EE + lane * 4);
    float4 p = *(const float4*)(wpe + (size_t)s  * EE + lane * 4);
    float4 v = { a.x + p.x, a.y + p.y, a.z + p.z, a.w + p.w };
    *(float4*)(h + (size_t)row * EE + lane * 4) = v;
    float sm  = v.x + v.y + v.z + v.w;
    float ss2 = v.x*v.x + v.y*v.y + v.z*v.z + v.w*v.w;
    #pragma unroll
    for (int off = 32; off; off >>= 1) {
        sm  += __shfl_xor(sm,  off);
        ss2 += __shfl_xor(ss2, off);
    }
    float mu  = sm * (1.f / EE);
    float var = ss2 * (1.f / EE) - mu * mu;
    float rs  = rsqrtf(var + 1e-5f);
    float4 gv = *(const float4*)(g + lane * 4);
    float4 bv = *(const float4*)(b + lane * 4);
    ushort4 w = { f2bf((v.x - mu) * rs * gv.x + bv.x),
                  f2bf((v.y - mu) * rs * gv.y + bv.y),
                  f2bf((v.z - mu) * rs * gv.z + bv.z),
                  f2bf((v.w - mu) * rs * gv.w + bv.w) };
    *(ushort4*)(x + (size_t)row * EE + lane * 4) = w;
}

// ---------------------------------------------------------------------------
// LayerNorm over E=256; 4 rows per 256-thread block (wave per row).
template<bool OUTBF>
__global__ __launch_bounds__(256) void ln_kernel(
    const float* __restrict__ in, const float* __restrict__ g,
    const float* __restrict__ b, void* __restrict__ out)
{
    int row  = blockIdx.x * 4 + (threadIdx.x >> 6);
    int lane = threadIdx.x & 63;
    float4 v = *(const float4*)(in + (size_t)row * EE + lane * 4);
    float s  = v.x + v.y + v.z + v.w;
    float ss = v.x*v.x + v.y*v.y + v.z*v.z + v.w*v.w;
    #pragma unroll
    for (int off = 32; off; off >>= 1) {
        s  += __shfl_xor(s,  off);
        ss += __shfl_xor(ss, off);
    }
    float mu  = s * (1.f / EE);
    float var = ss * (1.f / EE) - mu * mu;
    float rs  = rsqrtf(var + 1e-5f);
    float4 gv = *(const float4*)(g + lane * 4);
    float4 bv = *(const float4*)(b + lane * 4);
    float4 o;
    o.x = (v.x - mu) * rs * gv.x + bv.x;
    o.y = (v.y - mu) * rs * gv.y + bv.y;
    o.z = (v.z - mu) * rs * gv.z + bv.z;
    o.w = (v.w - mu) * rs * gv.w + bv.w;
    if (OUTBF) {
        ushort4 w = { f2bf(o.x), f2bf(o.y), f2bf(o.z), f2bf(o.w) };
        *(ushort4*)((ushort_t*)out + (size_t)row * EE + lane * 4) = w;
    } else {
        *(float4*)((float*)out + (size_t)row * EE + lane * 4) = o;
    }
}

// ---------------------------------------------------------------------------
// Merged weight transpose+convert: all 8 jobs (4 weights x 2 layers), one
// launch. Grid (768, 2): t<192 qkv | <256 proj | <512 fc1 | else fc2.
__global__ __launch_bounds__(256) void wconv_all(
    const float* __restrict__ qkv_w, const float* __restrict__ proj_w,
    const float* __restrict__ fc1_w, const float* __restrict__ fc2_w,
    ushort_t* __restrict__ wq_t, ushort_t* __restrict__ wp_t,
    ushort_t* __restrict__ w1_t, ushort_t* __restrict__ w2_t)
{
    __shared__ float t_[32][33];
    int l = blockIdx.y, t = blockIdx.x;
    const float* W; ushort_t* Wt; int K, N, n0, k0;
    if (t < 192)      { W = qkv_w  + (size_t)l*EE*3*EE; Wt = wq_t + (size_t)l*3*EE*EE;
                        K = EE; N = 3*EE; int u = t;       n0 = (u % 24) * 32; k0 = (u / 24) * 32; }
    else if (t < 256) { W = proj_w + (size_t)l*EE*EE;   Wt = wp_t + (size_t)l*EE*EE;
                        K = EE; N = EE;   int u = t - 192; n0 = (u % 8)  * 32; k0 = (u / 8)  * 32; }
    else if (t < 512) { W = fc1_w  + (size_t)l*EE*NI;   Wt = w1_t + (size_t)l*EE*NI;
                        K = EE; N = NI;   int u = t - 256; n0 = (u % 32) * 32; k0 = (u / 32) * 32; }
    else              { W = fc2_w  + (size_t)l*NI*EE;   Wt = w2_t + (size_t)l*NI*EE;
                        K = NI; N = EE;   int u = t - 512; n0 = (u % 8)  * 32; k0 = (u / 8)  * 32; }
    int tx = threadIdx.x & 31, ty = threadIdx.x >> 5;
    #pragma unroll
    for (int i = 0; i < 4; ++i) {
        int k = ty + i * 8;
        t_[k][tx] = W[(size_t)(k0 + k) * N + n0 + tx];
    }
    __syncthreads();
    #pragma unroll
    for (int i = 0; i < 4; ++i) {
        int n = ty + i * 8;
        Wt[(size_t)(n0 + n) * K + k0 + tx] = f2bf(t_[tx][n]);
    }
}

// ---------------------------------------------------------------------------
// bf16 MFMA GEMM (r22 structure: 2-stage reg pipeline, lgkm-only barriers,
// XCD remap, hw-exp2 GELU, optional fused split-K attention merge on A).
template<int MI, bool OUT_BF, bool GELU_ACT, bool RES, bool QSC, bool MERGEA>
__global__ __launch_bounds__(256) void gemm_bf(
    const ushort_t* __restrict__ A, const ushort_t* __restrict__ Bt,
    const float* __restrict__ bias, const float* __restrict__ res,
    void* __restrict__ C, const float* __restrict__ lp,
    int M, int N, int K)
{
    __shared__ __align__(16) ushort_t As[MI*64][40];
    __shared__ __align__(16) ushort_t Bs[64][40];
    int tid = threadIdx.x;
    int wid = tid >> 6, lane = tid & 63;
    int h = lane >> 4, c = lane & 15;

    // XCD-grouped remap (all our grids have nwg % 8 == 0)
    int nbx = gridDim.x;
    int nwg = nbx * gridDim.y;
    int flat = blockIdx.y * nbx + blockIdx.x;
    int v = (flat & 7) * (nwg >> 3) + (flat >> 3);
    int bx = v % nbx, by = v / nbx;

    f32x4 acc[MI][4] = {};

    int arow = tid >> 2, ac = tid & 3;
    const ushort_t* Ap = A  + (size_t)(by * (MI*64) + arow) * K + ac * 8;
    const ushort_t* Bp = Bt + (size_t)(bx * 64     + arow) * K + ac * 8;

    // MERGEA per-thread row state (MI==1 for merge path)
    int mb = 0, msr = 0, mnp = 0, colbase = ac * 8;
    if (MERGEA) {
        int mrow = by * 64 + arow;
        mb  = mrow >> 11;            // / SS
        msr = mrow & (SS - 1);
        mnp = ((msr >> 6) >> 3) + 1; // 1..4 pieces
    }

    // two register stages
    s16x8 a0[MI], a1[MI], b0, b1;
    s16x8 mo0[4], mo1[4];
    float ml0[4], ml1[4];

    #define M_ISSUE(kk, MO, ML) do {                                          \
        int col = (kk) + colbase;                                             \
        int hh2 = col >> 5, d0 = col & 31;                                    \
        size_t rl = ((size_t)(mb * HH + hh2)) * SS + msr;                     \
        _Pragma("unroll")                                                     \
        for (int i_ = 0; i_ < 4; ++i_) {                                      \
            if (i_ < mnp) {                                                   \
                MO[i_] = *(const s16x8*)(A + ((size_t)i_ * NRL + rl) * DD + d0); \
                ML[i_] = lp[(size_t)i_ * NRL + rl];                           \
            } else { MO[i_] = (s16x8){0,0,0,0,0,0,0,0}; ML[i_] = 0.f; }       \
        }                                                                     \
    } while (0)

    #define M_COMBINE(MO, ML, OUTV) do {                                      \
        float L_ = ML[0] + ML[1] + ML[2] + ML[3];                             \
        float inv_ = __builtin_amdgcn_rcpf(L_);                               \
        _Pragma("unroll")                                                     \
        for (int e_ = 0; e_ < 8; ++e_) {                                      \
            float s_ = bf2f((ushort_t)MO[0][e_]) + bf2f((ushort_t)MO[1][e_])  \
                     + bf2f((ushort_t)MO[2][e_]) + bf2f((ushort_t)MO[3][e_]); \
            OUTV[e_] = (short)f2bf(s_ * inv_);                                \
        }                                                                     \
    } while (0)

    // prologue: two stages in flight
    if (MERGEA) { M_ISSUE(0, mo0, ml0); M_ISSUE(32, mo1, ml1); }
    else {
        #pragma unroll
        for (int i = 0; i < MI; ++i) a0[i] = *(const s16x8*)(Ap + (size_t)i * 64 * K);
        #pragma unroll
        for (int i = 0; i < MI; ++i) a1[i] = *(const s16x8*)(Ap + (size_t)i * 64 * K + 32);
    }
    b0 = *(const s16x8*)(Bp);
    b1 = *(const s16x8*)(Bp + 32);

    for (int k0 = 0; k0 < K; k0 += 64) {
        // ---- half A: consume stage0 (k0), prefetch k0+64 ----
        asm volatile("s_waitcnt lgkmcnt(0)" ::: "memory");
        __builtin_amdgcn_s_barrier();      // WAR: prev half's LDS reads done
        asm volatile("" ::: "memory");
        if (MERGEA) {
            s16x8 mv; M_COMBINE(mo0, ml0, mv);
            *(s16x8*)&As[arow][ac * 8] = mv;
        } else {
            #pragma unroll
            for (int i = 0; i < MI; ++i)
                *(s16x8*)&As[i * 64 + arow][ac * 8] = a0[i];
        }
        *(s16x8*)&Bs[arow][ac * 8] = b0;
        if (k0 + 64 < K) {
            if (MERGEA) M_ISSUE(k0 + 64, mo0, ml0);
            else {
                #pragma unroll
                for (int i = 0; i < MI; ++i)
                    a0[i] = *(const s16x8*)(Ap + (size_t)i * 64 * K + k0 + 64);
            }
            b0 = *(const s16x8*)(Bp + k0 + 64);
        }
        asm volatile("s_waitcnt lgkmcnt(0)" ::: "memory");
        __builtin_amdgcn_s_barrier();      // RAW: tile visible
        asm volatile("" ::: "memory");
        {
            s16x8 af[MI], bfr[4];
            #pragma unroll
            for (int i = 0; i < MI; ++i)
                af[i] = *(const s16x8*)&As[wid * (MI*16) + i * 16 + c][h * 8];
            #pragma unroll
            for (int j = 0; j < 4; ++j)
                bfr[j] = *(const s16x8*)&Bs[j * 16 + c][h * 8];
            #pragma unroll
            for (int i = 0; i < MI; ++i)
                #pragma unroll
                for (int j = 0; j < 4; ++j)
                    acc[i][j] = mfma16x16x32(af[i], bfr[j], acc[i][j]);
        }
        // ---- half B: consume stage1 (k0+32), prefetch k0+96 ----
        asm volatile("s_waitcnt lgkmcnt(0)" ::: "memory");
        __builtin_amdgcn_s_barrier();
        asm volatile("" ::: "memory");
        if (MERGEA) {
            s16x8 mv; M_COMBINE(mo1, ml1, mv);
            *(s16x8*)&As[arow][ac * 8] = mv;
        } else {
            #pragma unroll
            for (int i = 0; i < MI; ++i)
                *(s16x8*)&As[i * 64 + arow][ac * 8] = a1[i];
        }
        *(s16x8*)&Bs[arow][ac * 8] = b1;
        if (k0 + 96 < K) {
            if (MERGEA) M_ISSUE(k0 + 96, mo1, ml1);
            else {
                #pragma unroll
                for (int i = 0; i < MI; ++i)
                    a1[i] = *(const s16x8*)(Ap + (size_t)i * 64 * K + k0 + 96);
            }
            b1 = *(const s16x8*)(Bp + k0 + 96);
        }
        asm volatile("s_waitcnt lgkmcnt(0)" ::: "memory");
        __builtin_amdgcn_s_barrier();
        asm volatile("" ::: "memory");
        {
            s16x8 af[MI], bfr[4];
            #pragma unroll
            for (int i = 0; i < MI; ++i)
                af[i] = *(const s16x8*)&As[wid * (MI*16) + i * 16 + c][h * 8];
            #pragma unroll
            for (int j = 0; j < 4; ++j)
                bfr[j] = *(const s16x8*)&Bs[j * 16 + c][h * 8];
            #pragma unroll
            for (int i = 0; i < MI; ++i)
                #pragma unroll
                for (int j = 0; j < 4; ++j)
                    acc[i][j] = mfma16x16x32(af[i], bfr[j], acc[i][j]);
        }
    }
    #undef M_ISSUE
    #undef M_COMBINE

    float bj[4];
    #pragma unroll
    for (int j = 0; j < 4; ++j) bj[j] = bias[bx * 64 + j * 16 + c];
    #pragma unroll
    for (int i = 0; i < MI; ++i) {
        #pragma unroll
        for (int r = 0; r < 4; ++r) {
            int row = by * (MI*64) + wid * (MI*16) + i * 16 + h * 4 + r;
            #pragma unroll
            for (int j = 0; j < 4; ++j) {
                int col = bx * 64 + j * 16 + c;
                float v2 = acc[i][j][r] + bj[j];
                if (QSC && col < EE) v2 *= QSCALE;
                if (RES) v2 += res[(size_t)row * N + col];
                if (GELU_ACT) {
                    float u = 0.7978845608028654f * (v2 + 0.044715f * v2 * v2 * v2);
                    float t = exp2f(2.8853900817779268f * u);   // e^(2u)
                    v2 = v2 - v2 * __builtin_amdgcn_rcpf(t + 1.f); // v*t/(t+1)
                }
                if (OUT_BF) ((ushort_t*)C)[(size_t)row * N + col] = f2bf(v2);
                else        ((float*)C)[(size_t)row * N + col]    = v2;
            }
        }
    }
}

// ---------------------------------------------------------------------------
// Split-K causal flash attention (partial pass). PTILES=8, 80 pieces/(b,h),
// 64-key tiles, reg-prefetch + lgkm-only barrier, max-free softmax, l via
// ones-MFMA, swapped-QK packed Ps writes (r20/r22 structure, 39.5us —
// r23's K-direct-from-global regressed to 52us: uncoalesced per-lane frag
// loads + VGPR 48->56 occupancy loss; REVERTED).
#define QB 64
#define KSTR 40
#define VSTR 88
#define PSTR 72
#define PTILES 8
__global__ __launch_bounds__(256) void attn_kernel(
    const ushort_t* __restrict__ qkv, ushort_t* __restrict__ o_part,
    float* __restrict__ l_part)
{
    __shared__ __align__(16) ushort_t Ks[QB][KSTR];
    __shared__ __align__(16) ushort_t Vt[DD][VSTR];
    __shared__ __align__(16) ushort_t Ps[4][16][PSTR];

    int tid  = threadIdx.x;
    int p    = 79 - blockIdx.x;              // heavy (high qt) first
    int qt, ks;
    if (p < 8)       { qt = p;                 ks = 0; }
    else if (p < 24) { qt = 8  + ((p-8)  >> 1); ks = (p-8)  & 1; }
    else if (p < 48) { qt = 16 + (p-24) / 3;    ks = (p-24) % 3; }
    else             { qt = 24 + ((p-48) >> 2); ks = (p-48) & 3; }
    int hh   = blockIdx.y, b = blockIdx.z;
    int wid  = tid >> 6, lane = tid & 63;
    int h    = lane >> 4, c = lane & 15;

    int qfrow = qt * QB + wid * 16 + c;
    s16x8 qfrag = *(const s16x8*)(qkv + ((size_t)(b * SS + qfrow)) * (3*EE)
                                  + hh * DD + h * 8);

    s16x8 onesf = { (short)0x3F80, (short)0x3F80, (short)0x3F80, (short)0x3F80,
                    (short)0x3F80, (short)0x3F80, (short)0x3F80, (short)0x3F80 };

    f32x4 o0 = {0.f,0.f,0.f,0.f}, o1 = {0.f,0.f,0.f,0.f}, o2 = {0.f,0.f,0.f,0.f};

    int srow = tid >> 2, scq = tid & 3;
    int t0 = ks * PTILES;
    int t1 = min(t0 + PTILES, qt + 1);

    s16x8 kreg, vreg;
    {
        const ushort_t* kb = qkv + ((size_t)(b * SS + t0 * QB)) * (3*EE) + hh * DD + EE;
        kreg = *(const s16x8*)(kb + (size_t)srow * (3*EE) + scq * 8);
        vreg = *(const s16x8*)(kb + EE + (size_t)srow * (3*EE) + scq * 8);
    }

    for (int kt = t0; kt < t1; ++kt) {
        int k0 = kt * QB;

        __syncthreads();   // prev tile's LDS reads done

        *(s16x8*)&Ks[srow][scq * 8] = kreg;
        {
            int d0 = scq * 8;
            int colw = srow ^ (scq << 4);          // XOR swizzle
            #pragma unroll
            for (int j = 0; j < 8; ++j) Vt[d0 + j][colw] = (ushort_t)vreg[j];
        }
        if (kt + 1 < t1) {
            const ushort_t* kb2 = qkv + ((size_t)(b * SS + (kt+1) * QB)) * (3*EE)
                                  + hh * DD + EE;
            kreg = *(const s16x8*)(kb2 + (size_t)srow * (3*EE) + scq * 8);
            vreg = *(const s16x8*)(kb2 + EE + (size_t)srow * (3*EE) + scq * 8);
        }

        asm volatile("s_waitcnt lgkmcnt(0)" ::: "memory");
        __builtin_amdgcn_s_barrier();
        asm volatile("" ::: "memory");

        __builtin_amdgcn_s_setprio(1);

        // QK (swapped): lane holds S[q=c][key = g*16 + h*4 + r]
        f32x4 sg[4];
        #pragma unroll
        for (int g = 0; g < 4; ++g) {
            s16x8 kf = *(const s16x8*)&Ks[g * 16 + c][h * 8];
            f32x4 z = {0.f,0.f,0.f,0.f};
            sg[g] = mfma16x16x32(kf, qfrag, z);
        }

        if (kt == qt) {                       // diagonal tile: masked path
            int klim = qfrow - k0;
            #pragma unroll
            for (int g = 0; g < 4; ++g) {
                ushort4 pk;
                #pragma unroll
                for (int r = 0; r < 4; ++r) {
                    float x = sg[g][r];
                    if (g * 16 + h * 4 + r > klim) x = -INFINITY;
                    ((ushort_t*)&pk)[r] = f2bf(exp2f(x));
                }
                *(ushort4*)&Ps[wid][c][g * 16 + h * 4] = pk;
            }
        } else {                              // interior tile: no masking
            #pragma unroll
            for (int g = 0; g < 4; ++g) {
                ushort4 pk;
                #pragma unroll
                for (int r = 0; r < 4; ++r)
                    ((ushort_t*)&pk)[r] = f2bf(exp2f(sg[g][r]));
                *(ushort4*)&Ps[wid][c][g * 16 + h * 4] = pk;
            }
        }

        #pragma unroll
        for (int kc = 0; kc < 2; ++kc) {
            int kbase = kc * 32 + h * 8;
            s16x8 pf = *(const s16x8*)&Ps[wid][c][kbase];
            s16x8 v0 = *(const s16x8*)&Vt[c]     [kbase ^ ((c >> 3) << 4)];
            s16x8 v1 = *(const s16x8*)&Vt[16 + c][kbase ^ (((16 + c) >> 3) << 4)];
            o0 = mfma16x16x32(pf, v0, o0);
            o1 = mfma16x16x32(pf, v1, o1);
            o2 = mfma16x16x32(pf, onesf, o2);   // row sums -> l
        }

        __builtin_amdgcn_s_setprio(0);
    }

    // write partials for ALL rows (merge fused into proj GEMM)
    size_t rbase = (size_t)(b * HH + hh) * SS;
    #pragma unroll
    for (int r = 0; r < 4; ++r) {
        int qrow = qt * QB + wid * 16 + h * 4 + r;
        size_t rl = rbase + qrow;
        ushort_t* op = o_part + ((size_t)ks * NRL + rl) * DD;
        op[c]      = f2bf(o0[r]);
        op[16 + c] = f2bf(o1[r]);
        if (c == 0) l_part[(size_t)ks * NRL + rl] = o2[r];
    }
}

// ---------------------------------------------------------------------------
extern "C" void kernel_launch(void* const* d_in, const int* in_sizes, int n_in,
                              void* d_out, int out_size, void* d_ws, size_t ws_size,
                              hipStream_t stream)
{
    const int*   ids    = (const int*)  d_in[0];
    const float* wte    = (const float*)d_in[1];
    const float* wpe    = (const float*)d_in[2];
    const float* ln1_g  = (const float*)d_in[3];
    const float* ln1_b  = (const float*)d_in[4];
    const float* qkv_w  = (const float*)d_in[5];
    const float* qkv_b  = (const float*)d_in[6];
    const float* proj_w = (const float*)d_in[7];
    const float* proj_b = (const float*)d_in[8];
    const float* ln2_g  = (const float*)d_in[9];
    const float* ln2_b  = (const float*)d_in[10];
    const float* fc1_w  = (const float*)d_in[11];
    const float* fc1_b  = (const float*)d_in[12];
    const float* fc2_w  = (const float*)d_in[13];
    const float* fc2_b  = (const float*)d_in[14];
    const float* lnf_g  = (const float*)d_in[15];
    const float* lnf_b  = (const float*)d_in[16];

    float*    h        = (float*)d_ws;                         // 8192*256 f32
    ushort_t* x_bf     = (ushort_t*)(h + (size_t)NROWS*EE);    // 8192*256
    ushort_t* qkv_bf   = x_bf   + (size_t)NROWS*EE;            // 8192*768
    ushort_t* attno_bf = qkv_bf + (size_t)NROWS*3*EE;          // 8192*256 (spare)
    ushort_t* m1_bf    = attno_bf + (size_t)NROWS*EE;          // 8192*1024
    ushort_t* wq_t     = m1_bf  + (size_t)NROWS*NI;            // [2][768][256]
    ushort_t* wp_t     = wq_t   + (size_t)2*3*EE*EE;           // [2][256][256]
    ushort_t* w1_t     = wp_t   + (size_t)2*EE*EE;             // [2][1024][256]
    ushort_t* w2_t     = w1_t   + (size_t)2*EE*NI;             // [2][256][1024]

    // split-K scratch overlays (regions dead during attention + proj):
    ushort_t* o_part   = m1_bf;              // 4*65536*32*2B = 16.78MB == m1 region
    float*    l_part   = (float*)x_bf;       // 4*65536*4B    = 1.05MB  <  x region

    wconv_all<<<dim3(768, LL), 256, 0, stream>>>(
        qkv_w, proj_w, fc1_w, fc2_w, wq_t, wp_t, w1_t, w2_t);

    embed_ln_kernel<<<NROWS/4, 256, 0, stream>>>(ids, wte, wpe, ln1_g, ln1_b, h, x_bf);

    for (int l = 0; l < LL; ++l) {
        if (l > 0)
            ln_kernel<true><<<NROWS/4, 256, 0, stream>>>(h, ln1_g + l*EE, ln1_b + l*EE, x_bf);
        gemm_bf<2,true,false,false,true,false><<<dim3(3*EE/64, NROWS/128), 256, 0, stream>>>(
            x_bf, wq_t + (size_t)l*3*EE*EE, qkv_b + (size_t)l*3*EE, nullptr,
            qkv_bf, nullptr, NROWS, 3*EE, EE);
        attn_kernel<<<dim3(80, HH, BB), 256, 0, stream>>>(qkv_bf, o_part, l_part);
        // proj GEMM with fused split-K merge (A = o_part + l_part)
        gemm_bf<1,false,false,true,false,true><<<dim3(EE/64, NROWS/64), 256, 0, stream>>>(
            o_part, wp_t + (size_t)l*EE*EE, proj_b + (size_t)l*EE, h,
            h, l_part, NROWS, EE, EE);
        ln_kernel<true><<<NROWS/4, 256, 0, stream>>>(h, ln2_g + l*EE, ln2_b + l*EE, x_bf);
        gemm_bf<2,true,true,false,false,false><<<dim3(NI/64, NROWS/128), 256, 0, stream>>>(
            x_bf, w1_t + (size_t)l*EE*NI, fc1_b + (size_t)l*NI, nullptr,
            m1_bf, nullptr, NROWS, NI, EE);
        gemm_bf<1,false,false,true,false,false><<<dim3(EE/64, NROWS/64), 256, 0, stream>>>(
            m1_bf, w2_t + (size_t)l*NI*EE, fc2_b + (size_t)l*EE, h,
            h, nullptr, NROWS, EE, NI);
    }

    ln_kernel<false><<<NROWS/4, 256, 0, stream>>>(h, lnf_g, lnf_b, (float*)d_out);
}

// Round 25
// 182.389 us; speedup vs baseline: 1.1852x; 1.0021x over previous
//
#include <hip/hip_runtime.h>
#include <hip/hip_bf16.h>
#include <math.h>

// Problem dims (fixed by reference)
#define BB 4
#define SS 2048
#define EE 256
#define HH 8
#define DD 32
#define LL 2
#define NI 1024
#define NROWS (BB*SS)   // 8192
#define NRL   (BB*HH*SS) // 65536 flat (b,h,s) rows

typedef float f32x4 __attribute__((ext_vector_type(4)));
typedef short s16x8 __attribute__((ext_vector_type(8)));
typedef __bf16 bf16x8 __attribute__((ext_vector_type(8)));
typedef unsigned short ushort_t;

// 1/sqrt(32) * log2(e): QK scores land in log2 domain -> exp2f everywhere.
#define QSCALE 0.2550352699458294f

__device__ __forceinline__ unsigned short f2bf(float f) {
    return __builtin_bit_cast(unsigned short, (__bf16)f);   // native RNE cvt
}
__device__ __forceinline__ float bf2f(unsigned short s) {
    return __uint_as_float((unsigned)s << 16);
}
__device__ __forceinline__ f32x4 mfma16x16x32(s16x8 a, s16x8 b, f32x4 c) {
    return __builtin_amdgcn_mfma_f32_16x16x32_bf16(
        __builtin_bit_cast(bf16x8, a), __builtin_bit_cast(bf16x8, b), c, 0, 0, 0);
}

// ---------------------------------------------------------------------------
// Fused embedding + LN1(layer 0): h = wte[id]+wpe; x_bf = LN(h,g,b).
__global__ __launch_bounds__(256) void embed_ln_kernel(
    const int* __restrict__ ids, const float* __restrict__ wte,
    const float* __restrict__ wpe, const float* __restrict__ g,
    const float* __restrict__ b, float* __restrict__ h, ushort_t* __restrict__ x)
{
    int row  = blockIdx.x * 4 + (threadIdx.x >> 6);
    int s    = row & (SS - 1);
    int lane = threadIdx.x & 63;
    int id   = ids[row];
    float4 a = *(const float4*)(wte + (size_t)id * EE + lane * 4);
    float4 p = *(const float4*)(wpe + (size_t)s  * EE + lane * 4);
    float4 v = { a.x + p.x, a.y + p.y, a.z + p.z, a.w + p.w };
    *(float4*)(h + (size_t)row * EE + lane * 4) = v;
    float sm  = v.x + v.y + v.z + v.w;
    float ss2 = v.x*v.x + v.y*v.y + v.z*v.z + v.w*v.w;
    #pragma unroll
    for (int off = 32; off; off >>= 1) {
        sm  += __shfl_xor(sm,  off);
        ss2 += __shfl_xor(ss2, off);
    }
    float mu  = sm * (1.f / EE);
    float var = ss2 * (1.f / EE) - mu * mu;
    float rs  = rsqrtf(var + 1e-5f);
    float4 gv = *(const float4*)(g + lane * 4);
    float4 bv = *(const float4*)(b + lane * 4);
    ushort4 w = { f2bf((v.x - mu) * rs * gv.x + bv.x),
                  f2bf((v.y - mu) * rs * gv.y + bv.y),
                  f2bf((v.z - mu) * rs * gv.z + bv.z),
                  f2bf((v.w - mu) * rs * gv.w + bv.w) };
    *(ushort4*)(x + (size_t)row * EE + lane * 4) = w;
}

// ---------------------------------------------------------------------------
// LayerNorm over E=256; 4 rows per 256-thread block (wave per row).
template<bool OUTBF>
__global__ __launch_bounds__(256) void ln_kernel(
    const float* __restrict__ in, const float* __restrict__ g,
    const float* __restrict__ b, void* __restrict__ out)
{
    int row  = blockIdx.x * 4 + (threadIdx.x >> 6);
    int lane = threadIdx.x & 63;
    float4 v = *(const float4*)(in + (size_t)row * EE + lane * 4);
    float s  = v.x + v.y + v.z + v.w;
    float ss = v.x*v.x + v.y*v.y + v.z*v.z + v.w*v.w;
    #pragma unroll
    for (int off = 32; off; off >>= 1) {
        s  += __shfl_xor(s,  off);
        ss += __shfl_xor(ss, off);
    }
    float mu  = s * (1.f / EE);
    float var = ss * (1.f / EE) - mu * mu;
    float rs  = rsqrtf(var + 1e-5f);
    float4 gv = *(const float4*)(g + lane * 4);
    float4 bv = *(const float4*)(b + lane * 4);
    float4 o;
    o.x = (v.x - mu) * rs * gv.x + bv.x;
    o.y = (v.y - mu) * rs * gv.y + bv.y;
    o.z = (v.z - mu) * rs * gv.z + bv.z;
    o.w = (v.w - mu) * rs * gv.w + bv.w;
    if (OUTBF) {
        ushort4 w = { f2bf(o.x), f2bf(o.y), f2bf(o.z), f2bf(o.w) };
        *(ushort4*)((ushort_t*)out + (size_t)row * EE + lane * 4) = w;
    } else {
        *(float4*)((float*)out + (size_t)row * EE + lane * 4) = o;
    }
}

// ---------------------------------------------------------------------------
// Merged weight transpose+convert: all 8 jobs (4 weights x 2 layers), one
// launch. Grid (768, 2): t<192 qkv | <256 proj | <512 fc1 | else fc2.
__global__ __launch_bounds__(256) void wconv_all(
    const float* __restrict__ qkv_w, const float* __restrict__ proj_w,
    const float* __restrict__ fc1_w, const float* __restrict__ fc2_w,
    ushort_t* __restrict__ wq_t, ushort_t* __restrict__ wp_t,
    ushort_t* __restrict__ w1_t, ushort_t* __restrict__ w2_t)
{
    __shared__ float t_[32][33];
    int l = blockIdx.y, t = blockIdx.x;
    const float* W; ushort_t* Wt; int K, N, n0, k0;
    if (t < 192)      { W = qkv_w  + (size_t)l*EE*3*EE; Wt = wq_t + (size_t)l*3*EE*EE;
                        K = EE; N = 3*EE; int u = t;       n0 = (u % 24) * 32; k0 = (u / 24) * 32; }
    else if (t < 256) { W = proj_w + (size_t)l*EE*EE;   Wt = wp_t + (size_t)l*EE*EE;
                        K = EE; N = EE;   int u = t - 192; n0 = (u % 8)  * 32; k0 = (u / 8)  * 32; }
    else if (t < 512) { W = fc1_w  + (size_t)l*EE*NI;   Wt = w1_t + (size_t)l*EE*NI;
                        K = EE; N = NI;   int u = t - 256; n0 = (u % 32) * 32; k0 = (u / 32) * 32; }
    else              { W = fc2_w  + (size_t)l*NI*EE;   Wt = w2_t + (size_t)l*NI*EE;
                        K = NI; N = EE;   int u = t - 512; n0 = (u % 8)  * 32; k0 = (u / 8)  * 32; }
    int tx = threadIdx.x & 31, ty = threadIdx.x >> 5;
    #pragma unroll
    for (int i = 0; i < 4; ++i) {
        int k = ty + i * 8;
        t_[k][tx] = W[(size_t)(k0 + k) * N + n0 + tx];
    }
    __syncthreads();
    #pragma unroll
    for (int i = 0; i < 4; ++i) {
        int n = ty + i * 8;
        Wt[(size_t)(n0 + n) * K + k0 + tx] = f2bf(t_[tx][n]);
    }
}

// ---------------------------------------------------------------------------
// bf16 MFMA GEMM (r22 structure: 2-stage reg pipeline, lgkm-only barriers,
// XCD remap, hw-exp2 GELU, optional fused split-K attention merge on A).
template<int MI, bool OUT_BF, bool GELU_ACT, bool RES, bool QSC, bool MERGEA>
__global__ __launch_bounds__(256) void gemm_bf(
    const ushort_t* __restrict__ A, const ushort_t* __restrict__ Bt,
    const float* __restrict__ bias, const float* __restrict__ res,
    void* __restrict__ C, const float* __restrict__ lp,
    int M, int N, int K)
{
    __shared__ __align__(16) ushort_t As[MI*64][40];
    __shared__ __align__(16) ushort_t Bs[64][40];
    int tid = threadIdx.x;
    int wid = tid >> 6, lane = tid & 63;
    int h = lane >> 4, c = lane & 15;

    // XCD-grouped remap (all our grids have nwg % 8 == 0)
    int nbx = gridDim.x;
    int nwg = nbx * gridDim.y;
    int flat = blockIdx.y * nbx + blockIdx.x;
    int v = (flat & 7) * (nwg >> 3) + (flat >> 3);
    int bx = v % nbx, by = v / nbx;

    f32x4 acc[MI][4] = {};

    int arow = tid >> 2, ac = tid & 3;
    const ushort_t* Ap = A  + (size_t)(by * (MI*64) + arow) * K + ac * 8;
    const ushort_t* Bp = Bt + (size_t)(bx * 64     + arow) * K + ac * 8;

    // MERGEA per-thread row state (MI==1 for merge path)
    int mb = 0, msr = 0, mnp = 0, colbase = ac * 8;
    if (MERGEA) {
        int mrow = by * 64 + arow;
        mb  = mrow >> 11;            // / SS
        msr = mrow & (SS - 1);
        mnp = ((msr >> 6) >> 3) + 1; // 1..4 pieces
    }

    // two register stages
    s16x8 a0[MI], a1[MI], b0, b1;
    s16x8 mo0[4], mo1[4];
    float ml0[4], ml1[4];

    #define M_ISSUE(kk, MO, ML) do {                                          \
        int col = (kk) + colbase;                                             \
        int hh2 = col >> 5, d0 = col & 31;                                    \
        size_t rl = ((size_t)(mb * HH + hh2)) * SS + msr;                     \
        _Pragma("unroll")                                                     \
        for (int i_ = 0; i_ < 4; ++i_) {                                      \
            if (i_ < mnp) {                                                   \
                MO[i_] = *(const s16x8*)(A + ((size_t)i_ * NRL + rl) * DD + d0); \
                ML[i_] = lp[(size_t)i_ * NRL + rl];                           \
            } else { MO[i_] = (s16x8){0,0,0,0,0,0,0,0}; ML[i_] = 0.f; }       \
        }                                                                     \
    } while (0)

    #define M_COMBINE(MO, ML, OUTV) do {                                      \
        float L_ = ML[0] + ML[1] + ML[2] + ML[3];                             \
        float inv_ = __builtin_amdgcn_rcpf(L_);                               \
        _Pragma("unroll")                                                     \
        for (int e_ = 0; e_ < 8; ++e_) {                                      \
            float s_ = bf2f((ushort_t)MO[0][e_]) + bf2f((ushort_t)MO[1][e_])  \
                     + bf2f((ushort_t)MO[2][e_]) + bf2f((ushort_t)MO[3][e_]); \
            OUTV[e_] = (short)f2bf(s_ * inv_);                                \
        }                                                                     \
    } while (0)

    // prologue: two stages in flight
    if (MERGEA) { M_ISSUE(0, mo0, ml0); M_ISSUE(32, mo1, ml1); }
    else {
        #pragma unroll
        for (int i = 0; i < MI; ++i) a0[i] = *(const s16x8*)(Ap + (size_t)i * 64 * K);
        #pragma unroll
        for (int i = 0; i < MI; ++i) a1[i] = *(const s16x8*)(Ap + (size_t)i * 64 * K + 32);
    }
    b0 = *(const s16x8*)(Bp);
    b1 = *(const s16x8*)(Bp + 32);

    for (int k0 = 0; k0 < K; k0 += 64) {
        // ---- half A: consume stage0 (k0), prefetch k0+64 ----
        asm volatile("s_waitcnt lgkmcnt(0)" ::: "memory");
        __builtin_amdgcn_s_barrier();      // WAR: prev half's LDS reads done
        asm volatile("" ::: "memory");
        if (MERGEA) {
            s16x8 mv; M_COMBINE(mo0, ml0, mv);
            *(s16x8*)&As[arow][ac * 8] = mv;
        } else {
            #pragma unroll
            for (int i = 0; i < MI; ++i)
                *(s16x8*)&As[i * 64 + arow][ac * 8] = a0[i];
        }
        *(s16x8*)&Bs[arow][ac * 8] = b0;
        if (k0 + 64 < K) {
            if (MERGEA) M_ISSUE(k0 + 64, mo0, ml0);
            else {
                #pragma unroll
                for (int i = 0; i < MI; ++i)
                    a0[i] = *(const s16x8*)(Ap + (size_t)i * 64 * K + k0 + 64);
            }
            b0 = *(const s16x8*)(Bp + k0 + 64);
        }
        asm volatile("s_waitcnt lgkmcnt(0)" ::: "memory");
        __builtin_amdgcn_s_barrier();      // RAW: tile visible
        asm volatile("" ::: "memory");
        {
            s16x8 af[MI], bfr[4];
            #pragma unroll
            for (int i = 0; i < MI; ++i)
                af[i] = *(const s16x8*)&As[wid * (MI*16) + i * 16 + c][h * 8];
            #pragma unroll
            for (int j = 0; j < 4; ++j)
                bfr[j] = *(const s16x8*)&Bs[j * 16 + c][h * 8];
            #pragma unroll
            for (int i = 0; i < MI; ++i)
                #pragma unroll
                for (int j = 0; j < 4; ++j)
                    acc[i][j] = mfma16x16x32(af[i], bfr[j], acc[i][j]);
        }
        // ---- half B: consume stage1 (k0+32), prefetch k0+96 ----
        asm volatile("s_waitcnt lgkmcnt(0)" ::: "memory");
        __builtin_amdgcn_s_barrier();
        asm volatile("" ::: "memory");
        if (MERGEA) {
            s16x8 mv; M_COMBINE(mo1, ml1, mv);
            *(s16x8*)&As[arow][ac * 8] = mv;
        } else {
            #pragma unroll
            for (int i = 0; i < MI; ++i)
                *(s16x8*)&As[i * 64 + arow][ac * 8] = a1[i];
        }
        *(s16x8*)&Bs[arow][ac * 8] = b1;
        if (k0 + 96 < K) {
            if (MERGEA) M_ISSUE(k0 + 96, mo1, ml1);
            else {
                #pragma unroll
                for (int i = 0; i < MI; ++i)
                    a1[i] = *(const s16x8*)(Ap + (size_t)i * 64 * K + k0 + 96);
            }
            b1 = *(const s16x8*)(Bp + k0 + 96);
        }
        asm volatile("s_waitcnt lgkmcnt(0)" ::: "memory");
        __builtin_amdgcn_s_barrier();
        asm volatile("" ::: "memory");
        {
            s16x8 af[MI], bfr[4];
            #pragma unroll
            for (int i = 0; i < MI; ++i)
                af[i] = *(const s16x8*)&As[wid * (MI*16) + i * 16 + c][h * 8];
            #pragma unroll
            for (int j = 0; j < 4; ++j)
                bfr[j] = *(const s16x8*)&Bs[j * 16 + c][h * 8];
            #pragma unroll
            for (int i = 0; i < MI; ++i)
                #pragma unroll
                for (int j = 0; j < 4; ++j)
                    acc[i][j] = mfma16x16x32(af[i], bfr[j], acc[i][j]);
        }
    }
    #undef M_ISSUE
    #undef M_COMBINE

    float bj[4];
    #pragma unroll
    for (int j = 0; j < 4; ++j) bj[j] = bias[bx * 64 + j * 16 + c];
    #pragma unroll
    for (int i = 0; i < MI; ++i) {
        #pragma unroll
        for (int r = 0; r < 4; ++r) {
            int row = by * (MI*64) + wid * (MI*16) + i * 16 + h * 4 + r;
            #pragma unroll
            for (int j = 0; j < 4; ++j) {
                int col = bx * 64 + j * 16 + c;
                float v2 = acc[i][j][r] + bj[j];
                if (QSC && col < EE) v2 *= QSCALE;
                if (RES) v2 += res[(size_t)row * N + col];
                if (GELU_ACT) {
                    float u = 0.7978845608028654f * (v2 + 0.044715f * v2 * v2 * v2);
                    float t = exp2f(2.8853900817779268f * u);   // e^(2u)
                    v2 = v2 - v2 * __builtin_amdgcn_rcpf(t + 1.f); // v*t/(t+1)
                }
                if (OUT_BF) ((ushort_t*)C)[(size_t)row * N + col] = f2bf(v2);
                else        ((float*)C)[(size_t)row * N + col]    = v2;
            }
        }
    }
}

// ---------------------------------------------------------------------------
// Split-K causal flash attention (partial pass). PTILES=8, 80 pieces/(b,h),
// 64-key tiles, reg-prefetch + lgkm-only barrier, max-free softmax, l via
// ones-MFMA, swapped-QK packed Ps writes (r22 structure, 39.5us).
// ROUND-25 (attention XCD-combo grouping, T1): consecutive blocks used to
// round-robin (b,h)-pieces across the 8 XCDs -> every XCD touched all 32
// K/V panels (8MB > 4MB L2, thrash; FETCH 29MB vs 12.6MB logical). Bijective
// remap (2560 = 8 XCDs x 4 combos x 80 pieces): XCD x serves combos
// 4x..4x+3 only -> 1MB K/V per XCD, L2-resident; re-reads become L2 hits.
// Heavy-first piece order preserved within each combo.
#define QB 64
#define KSTR 40
#define VSTR 88
#define PSTR 72
#define PTILES 8
__global__ __launch_bounds__(256) void attn_kernel(
    const ushort_t* __restrict__ qkv, ushort_t* __restrict__ o_part,
    float* __restrict__ l_part)
{
    __shared__ __align__(16) ushort_t Ks[QB][KSTR];
    __shared__ __align__(16) ushort_t Vt[DD][VSTR];
    __shared__ __align__(16) ushort_t Ps[4][16][PSTR];

    int tid  = threadIdx.x;
    // XCD-combo remap: flat -> (xcd, idx); xcd serves 4 (b,h) combos.
    int flat  = (blockIdx.z * HH + blockIdx.y) * 80 + blockIdx.x;
    int xcd   = flat & 7, idx = flat >> 3;        // idx 0..319
    int combo = xcd * 4 + (idx / 80);             // 0..31
    int piece = idx % 80;
    int p     = 79 - piece;                       // heavy (high qt) first
    int hh    = combo & 7, b = combo >> 3;
    int qt, ks;
    if (p < 8)       { qt = p;                 ks = 0; }
    else if (p < 24) { qt = 8  + ((p-8)  >> 1); ks = (p-8)  & 1; }
    else if (p < 48) { qt = 16 + (p-24) / 3;    ks = (p-24) % 3; }
    else             { qt = 24 + ((p-48) >> 2); ks = (p-48) & 3; }
    int wid  = tid >> 6, lane = tid & 63;
    int h    = lane >> 4, c = lane & 15;

    int qfrow = qt * QB + wid * 16 + c;
    s16x8 qfrag = *(const s16x8*)(qkv + ((size_t)(b * SS + qfrow)) * (3*EE)
                                  + hh * DD + h * 8);

    s16x8 onesf = { (short)0x3F80, (short)0x3F80, (short)0x3F80, (short)0x3F80,
                    (short)0x3F80, (short)0x3F80, (short)0x3F80, (short)0x3F80 };

    f32x4 o0 = {0.f,0.f,0.f,0.f}, o1 = {0.f,0.f,0.f,0.f}, o2 = {0.f,0.f,0.f,0.f};

    int srow = tid >> 2, scq = tid & 3;
    int t0 = ks * PTILES;
    int t1 = min(t0 + PTILES, qt + 1);

    s16x8 kreg, vreg;
    {
        const ushort_t* kb = qkv + ((size_t)(b * SS + t0 * QB)) * (3*EE) + hh * DD + EE;
        kreg = *(const s16x8*)(kb + (size_t)srow * (3*EE) + scq * 8);
        vreg = *(const s16x8*)(kb + EE + (size_t)srow * (3*EE) + scq * 8);
    }

    for (int kt = t0; kt < t1; ++kt) {
        int k0 = kt * QB;

        __syncthreads();   // prev tile's LDS reads done

        *(s16x8*)&Ks[srow][scq * 8] = kreg;
        {
            int d0 = scq * 8;
            int colw = srow ^ (scq << 4);          // XOR swizzle
            #pragma unroll
            for (int j = 0; j < 8; ++j) Vt[d0 + j][colw] = (ushort_t)vreg[j];
        }
        if (kt + 1 < t1) {
            const ushort_t* kb2 = qkv + ((size_t)(b * SS + (kt+1) * QB)) * (3*EE)
                                  + hh * DD + EE;
            kreg = *(const s16x8*)(kb2 + (size_t)srow * (3*EE) + scq * 8);
            vreg = *(const s16x8*)(kb2 + EE + (size_t)srow * (3*EE) + scq * 8);
        }

        asm volatile("s_waitcnt lgkmcnt(0)" ::: "memory");
        __builtin_amdgcn_s_barrier();
        asm volatile("" ::: "memory");

        __builtin_amdgcn_s_setprio(1);

        // QK (swapped): lane holds S[q=c][key = g*16 + h*4 + r]
        f32x4 sg[4];
        #pragma unroll
        for (int g = 0; g < 4; ++g) {
            s16x8 kf = *(const s16x8*)&Ks[g * 16 + c][h * 8];
            f32x4 z = {0.f,0.f,0.f,0.f};
            sg[g] = mfma16x16x32(kf, qfrag, z);
        }

        if (kt == qt) {                       // diagonal tile: masked path
            int klim = qfrow - k0;
            #pragma unroll
            for (int g = 0; g < 4; ++g) {
                ushort4 pk;
                #pragma unroll
                for (int r = 0; r < 4; ++r) {
                    float x = sg[g][r];
                    if (g * 16 + h * 4 + r > klim) x = -INFINITY;
                    ((ushort_t*)&pk)[r] = f2bf(exp2f(x));
                }
                *(ushort4*)&Ps[wid][c][g * 16 + h * 4] = pk;
            }
        } else {                              // interior tile: no masking
            #pragma unroll
            for (int g = 0; g < 4; ++g) {
                ushort4 pk;
                #pragma unroll
                for (int r = 0; r < 4; ++r)
                    ((ushort_t*)&pk)[r] = f2bf(exp2f(sg[g][r]));
                *(ushort4*)&Ps[wid][c][g * 16 + h * 4] = pk;
            }
        }

        #pragma unroll
        for (int kc = 0; kc < 2; ++kc) {
            int kbase = kc * 32 + h * 8;
            s16x8 pf = *(const s16x8*)&Ps[wid][c][kbase];
            s16x8 v0 = *(const s16x8*)&Vt[c]     [kbase ^ ((c >> 3) << 4)];
            s16x8 v1 = *(const s16x8*)&Vt[16 + c][kbase ^ (((16 + c) >> 3) << 4)];
            o0 = mfma16x16x32(pf, v0, o0);
            o1 = mfma16x16x32(pf, v1, o1);
            o2 = mfma16x16x32(pf, onesf, o2);   // row sums -> l
        }

        __builtin_amdgcn_s_setprio(0);
    }

    // write partials for ALL rows (merge fused into proj GEMM)
    size_t rbase = (size_t)(b * HH + hh) * SS;
    #pragma unroll
    for (int r = 0; r < 4; ++r) {
        int qrow = qt * QB + wid * 16 + h * 4 + r;
        size_t rl = rbase + qrow;
        ushort_t* op = o_part + ((size_t)ks * NRL + rl) * DD;
        op[c]      = f2bf(o0[r]);
        op[16 + c] = f2bf(o1[r]);
        if (c == 0) l_part[(size_t)ks * NRL + rl] = o2[r];
    }
}

// ---------------------------------------------------------------------------
extern "C" void kernel_launch(void* const* d_in, const int* in_sizes, int n_in,
                              void* d_out, int out_size, void* d_ws, size_t ws_size,
                              hipStream_t stream)
{
    const int*   ids    = (const int*)  d_in[0];
    const float* wte    = (const float*)d_in[1];
    const float* wpe    = (const float*)d_in[2];
    const float* ln1_g  = (const float*)d_in[3];
    const float* ln1_b  = (const float*)d_in[4];
    const float* qkv_w  = (const float*)d_in[5];
    const float* qkv_b  = (const float*)d_in[6];
    const float* proj_w = (const float*)d_in[7];
    const float* proj_b = (const float*)d_in[8];
    const float* ln2_g  = (const float*)d_in[9];
    const float* ln2_b  = (const float*)d_in[10];
    const float* fc1_w  = (const float*)d_in[11];
    const float* fc1_b  = (const float*)d_in[12];
    const float* fc2_w  = (const float*)d_in[13];
    const float* fc2_b  = (const float*)d_in[14];
    const float* lnf_g  = (const float*)d_in[15];
    const float* lnf_b  = (const float*)d_in[16];

    float*    h        = (float*)d_ws;                         // 8192*256 f32
    ushort_t* x_bf     = (ushort_t*)(h + (size_t)NROWS*EE);    // 8192*256
    ushort_t* qkv_bf   = x_bf   + (size_t)NROWS*EE;            // 8192*768
    ushort_t* attno_bf = qkv_bf + (size_t)NROWS*3*EE;          // 8192*256 (spare)
    ushort_t* m1_bf    = attno_bf + (size_t)NROWS*EE;          // 8192*1024
    ushort_t* wq_t     = m1_bf  + (size_t)NROWS*NI;            // [2][768][256]
    ushort_t* wp_t     = wq_t   + (size_t)2*3*EE*EE;           // [2][256][256]
    ushort_t* w1_t     = wp_t   + (size_t)2*EE*EE;             // [2][1024][256]
    ushort_t* w2_t     = w1_t   + (size_t)2*EE*NI;             // [2][256][1024]

    // split-K scratch overlays (regions dead during attention + proj):
    ushort_t* o_part   = m1_bf;              // 4*65536*32*2B = 16.78MB == m1 region
    float*    l_part   = (float*)x_bf;       // 4*65536*4B    = 1.05MB  <  x region

    wconv_all<<<dim3(768, LL), 256, 0, stream>>>(
        qkv_w, proj_w, fc1_w, fc2_w, wq_t, wp_t, w1_t, w2_t);

    embed_ln_kernel<<<NROWS/4, 256, 0, stream>>>(ids, wte, wpe, ln1_g, ln1_b, h, x_bf);

    for (int l = 0; l < LL; ++l) {
        if (l > 0)
            ln_kernel<true><<<NROWS/4, 256, 0, stream>>>(h, ln1_g + l*EE, ln1_b + l*EE, x_bf);
        gemm_bf<2,true,false,false,true,false><<<dim3(3*EE/64, NROWS/128), 256, 0, stream>>>(
            x_bf, wq_t + (size_t)l*3*EE*EE, qkv_b + (size_t)l*3*EE, nullptr,
            qkv_bf, nullptr, NROWS, 3*EE, EE);
        attn_kernel<<<dim3(80, HH, BB), 256, 0, stream>>>(qkv_bf, o_part, l_part);
        // proj GEMM with fused split-K merge (A = o_part + l_part)
        gemm_bf<1,false,false,true,false,true><<<dim3(EE/64, NROWS/64), 256, 0, stream>>>(
            o_part, wp_t + (size_t)l*EE*EE, proj_b + (size_t)l*EE, h,
            h, l_part, NROWS, EE, EE);
        ln_kernel<true><<<NROWS/4, 256, 0, stream>>>(h, ln2_g + l*EE, ln2_b + l*EE, x_bf);
        gemm_bf<2,true,true,false,false,false><<<dim3(NI/64, NROWS/128), 256, 0, stream>>>(
            x_bf, w1_t + (size_t)l*EE*NI, fc1_b + (size_t)l*NI, nullptr,
            m1_bf, nullptr, NROWS, NI, EE);
        gemm_bf<1,false,false,true,false,false><<<dim3(EE/64, NROWS/64), 256, 0, stream>>>(
            m1_bf, w2_t + (size_t)l*NI*EE, fc2_b + (size_t)l*EE, h,
            h, nullptr, NROWS, EE, NI);
    }

    ln_kernel<false><<<NROWS/4, 256, 0, stream>>>(h, lnf_g, lnf_b, (float*)d_out);
}

// Round 26
// 179.770 us; speedup vs baseline: 1.2024x; 1.0146x over previous
//
#include <hip/hip_runtime.h>
#include <hip/hip_bf16.h>
#include <math.h>

// Problem dims (fixed by reference)
#define BB 4
#define SS 2048
#define EE 256
#define HH 8
#define DD 32
#define LL 2
#define NI 1024
#define NROWS (BB*SS)   // 8192
#define NRL   (BB*HH*SS) // 65536 flat (b,h,s) rows

typedef float f32x4 __attribute__((ext_vector_type(4)));
typedef short s16x8 __attribute__((ext_vector_type(8)));
typedef __bf16 bf16x8 __attribute__((ext_vector_type(8)));
typedef unsigned short ushort_t;

// 1/sqrt(32) * log2(e): QK scores land in log2 domain -> exp2f everywhere.
#define QSCALE 0.2550352699458294f

__device__ __forceinline__ unsigned short f2bf(float f) {
    return __builtin_bit_cast(unsigned short, (__bf16)f);   // native RNE cvt
}
__device__ __forceinline__ float bf2f(unsigned short s) {
    return __uint_as_float((unsigned)s << 16);
}
__device__ __forceinline__ f32x4 mfma16x16x32(s16x8 a, s16x8 b, f32x4 c) {
    return __builtin_amdgcn_mfma_f32_16x16x32_bf16(
        __builtin_bit_cast(bf16x8, a), __builtin_bit_cast(bf16x8, b), c, 0, 0, 0);
}

// ---------------------------------------------------------------------------
// Fused embedding + LN1(layer 0): h = wte[id]+wpe; x_bf = LN(h,g,b).
__global__ __launch_bounds__(256) void embed_ln_kernel(
    const int* __restrict__ ids, const float* __restrict__ wte,
    const float* __restrict__ wpe, const float* __restrict__ g,
    const float* __restrict__ b, float* __restrict__ h, ushort_t* __restrict__ x)
{
    int row  = blockIdx.x * 4 + (threadIdx.x >> 6);
    int s    = row & (SS - 1);
    int lane = threadIdx.x & 63;
    int id   = ids[row];
    float4 a = *(const float4*)(wte + (size_t)id * EE + lane * 4);
    float4 p = *(const float4*)(wpe + (size_t)s  * EE + lane * 4);
    float4 v = { a.x + p.x, a.y + p.y, a.z + p.z, a.w + p.w };
    *(float4*)(h + (size_t)row * EE + lane * 4) = v;
    float sm  = v.x + v.y + v.z + v.w;
    float ss2 = v.x*v.x + v.y*v.y + v.z*v.z + v.w*v.w;
    #pragma unroll
    for (int off = 32; off; off >>= 1) {
        sm  += __shfl_xor(sm,  off);
        ss2 += __shfl_xor(ss2, off);
    }
    float mu  = sm * (1.f / EE);
    float var = ss2 * (1.f / EE) - mu * mu;
    float rs  = rsqrtf(var + 1e-5f);
    float4 gv = *(const float4*)(g + lane * 4);
    float4 bv = *(const float4*)(b + lane * 4);
    ushort4 w = { f2bf((v.x - mu) * rs * gv.x + bv.x),
                  f2bf((v.y - mu) * rs * gv.y + bv.y),
                  f2bf((v.z - mu) * rs * gv.z + bv.z),
                  f2bf((v.w - mu) * rs * gv.w + bv.w) };
    *(ushort4*)(x + (size_t)row * EE + lane * 4) = w;
}

// ---------------------------------------------------------------------------
// LayerNorm over E=256; 4 rows per 256-thread block (wave per row).
template<bool OUTBF>
__global__ __launch_bounds__(256) void ln_kernel(
    const float* __restrict__ in, const float* __restrict__ g,
    const float* __restrict__ b, void* __restrict__ out)
{
    int row  = blockIdx.x * 4 + (threadIdx.x >> 6);
    int lane = threadIdx.x & 63;
    float4 v = *(const float4*)(in + (size_t)row * EE + lane * 4);
    float s  = v.x + v.y + v.z + v.w;
    float ss = v.x*v.x + v.y*v.y + v.z*v.z + v.w*v.w;
    #pragma unroll
    for (int off = 32; off; off >>= 1) {
        s  += __shfl_xor(s,  off);
        ss += __shfl_xor(ss, off);
    }
    float mu  = s * (1.f / EE);
    float var = ss * (1.f / EE) - mu * mu;
    float rs  = rsqrtf(var + 1e-5f);
    float4 gv = *(const float4*)(g + lane * 4);
    float4 bv = *(const float4*)(b + lane * 4);
    float4 o;
    o.x = (v.x - mu) * rs * gv.x + bv.x;
    o.y = (v.y - mu) * rs * gv.y + bv.y;
    o.z = (v.z - mu) * rs * gv.z + bv.z;
    o.w = (v.w - mu) * rs * gv.w + bv.w;
    if (OUTBF) {
        ushort4 w = { f2bf(o.x), f2bf(o.y), f2bf(o.z), f2bf(o.w) };
        *(ushort4*)((ushort_t*)out + (size_t)row * EE + lane * 4) = w;
    } else {
        *(float4*)((float*)out + (size_t)row * EE + lane * 4) = o;
    }
}

// ---------------------------------------------------------------------------
// Merged weight transpose+convert: all 8 jobs (4 weights x 2 layers), one
// launch. Grid (768, 2): t<192 qkv | <256 proj | <512 fc1 | else fc2.
__global__ __launch_bounds__(256) void wconv_all(
    const float* __restrict__ qkv_w, const float* __restrict__ proj_w,
    const float* __restrict__ fc1_w, const float* __restrict__ fc2_w,
    ushort_t* __restrict__ wq_t, ushort_t* __restrict__ wp_t,
    ushort_t* __restrict__ w1_t, ushort_t* __restrict__ w2_t)
{
    __shared__ float t_[32][33];
    int l = blockIdx.y, t = blockIdx.x;
    const float* W; ushort_t* Wt; int K, N, n0, k0;
    if (t < 192)      { W = qkv_w  + (size_t)l*EE*3*EE; Wt = wq_t + (size_t)l*3*EE*EE;
                        K = EE; N = 3*EE; int u = t;       n0 = (u % 24) * 32; k0 = (u / 24) * 32; }
    else if (t < 256) { W = proj_w + (size_t)l*EE*EE;   Wt = wp_t + (size_t)l*EE*EE;
                        K = EE; N = EE;   int u = t - 192; n0 = (u % 8)  * 32; k0 = (u / 8)  * 32; }
    else if (t < 512) { W = fc1_w  + (size_t)l*EE*NI;   Wt = w1_t + (size_t)l*EE*NI;
                        K = EE; N = NI;   int u = t - 256; n0 = (u % 32) * 32; k0 = (u / 32) * 32; }
    else              { W = fc2_w  + (size_t)l*NI*EE;   Wt = w2_t + (size_t)l*NI*EE;
                        K = NI; N = EE;   int u = t - 512; n0 = (u % 8)  * 32; k0 = (u / 8)  * 32; }
    int tx = threadIdx.x & 31, ty = threadIdx.x >> 5;
    #pragma unroll
    for (int i = 0; i < 4; ++i) {
        int k = ty + i * 8;
        t_[k][tx] = W[(size_t)(k0 + k) * N + n0 + tx];
    }
    __syncthreads();
    #pragma unroll
    for (int i = 0; i < 4; ++i) {
        int n = ty + i * 8;
        Wt[(size_t)(n0 + n) * K + k0 + tx] = f2bf(t_[tx][n]);
    }
}

// ---------------------------------------------------------------------------
// bf16 MFMA GEMM (r22 structure: 2-stage reg pipeline, lgkm-only barriers,
// XCD remap, hw-exp2 GELU, optional fused split-K attention merge on A).
template<int MI, bool OUT_BF, bool GELU_ACT, bool RES, bool QSC, bool MERGEA>
__global__ __launch_bounds__(256) void gemm_bf(
    const ushort_t* __restrict__ A, const ushort_t* __restrict__ Bt,
    const float* __restrict__ bias, const float* __restrict__ res,
    void* __restrict__ C, const float* __restrict__ lp,
    int M, int N, int K)
{
    __shared__ __align__(16) ushort_t As[MI*64][40];
    __shared__ __align__(16) ushort_t Bs[64][40];
    int tid = threadIdx.x;
    int wid = tid >> 6, lane = tid & 63;
    int h = lane >> 4, c = lane & 15;

    // XCD-grouped remap (all our grids have nwg % 8 == 0)
    int nbx = gridDim.x;
    int nwg = nbx * gridDim.y;
    int flat = blockIdx.y * nbx + blockIdx.x;
    int v = (flat & 7) * (nwg >> 3) + (flat >> 3);
    int bx = v % nbx, by = v / nbx;

    f32x4 acc[MI][4] = {};

    int arow = tid >> 2, ac = tid & 3;
    const ushort_t* Ap = A  + (size_t)(by * (MI*64) + arow) * K + ac * 8;
    const ushort_t* Bp = Bt + (size_t)(bx * 64     + arow) * K + ac * 8;

    // MERGEA per-thread row state (MI==1 for merge path)
    int mb = 0, msr = 0, mnp = 0, colbase = ac * 8;
    if (MERGEA) {
        int mrow = by * 64 + arow;
        mb  = mrow >> 11;            // / SS
        msr = mrow & (SS - 1);
        mnp = ((msr >> 6) >> 3) + 1; // 1..4 pieces
    }

    // two register stages
    s16x8 a0[MI], a1[MI], b0, b1;
    s16x8 mo0[4], mo1[4];
    float ml0[4], ml1[4];

    #define M_ISSUE(kk, MO, ML) do {                                          \
        int col = (kk) + colbase;                                             \
        int hh2 = col >> 5, d0 = col & 31;                                    \
        size_t rl = ((size_t)(mb * HH + hh2)) * SS + msr;                     \
        _Pragma("unroll")                                                     \
        for (int i_ = 0; i_ < 4; ++i_) {                                      \
            if (i_ < mnp) {                                                   \
                MO[i_] = *(const s16x8*)(A + ((size_t)i_ * NRL + rl) * DD + d0); \
                ML[i_] = lp[(size_t)i_ * NRL + rl];                           \
            } else { MO[i_] = (s16x8){0,0,0,0,0,0,0,0}; ML[i_] = 0.f; }       \
        }                                                                     \
    } while (0)

    #define M_COMBINE(MO, ML, OUTV) do {                                      \
        float L_ = ML[0] + ML[1] + ML[2] + ML[3];                             \
        float inv_ = __builtin_amdgcn_rcpf(L_);                               \
        _Pragma("unroll")                                                     \
        for (int e_ = 0; e_ < 8; ++e_) {                                      \
            float s_ = bf2f((ushort_t)MO[0][e_]) + bf2f((ushort_t)MO[1][e_])  \
                     + bf2f((ushort_t)MO[2][e_]) + bf2f((ushort_t)MO[3][e_]); \
            OUTV[e_] = (short)f2bf(s_ * inv_);                                \
        }                                                                     \
    } while (0)

    // prologue: two stages in flight
    if (MERGEA) { M_ISSUE(0, mo0, ml0); M_ISSUE(32, mo1, ml1); }
    else {
        #pragma unroll
        for (int i = 0; i < MI; ++i) a0[i] = *(const s16x8*)(Ap + (size_t)i * 64 * K);
        #pragma unroll
        for (int i = 0; i < MI; ++i) a1[i] = *(const s16x8*)(Ap + (size_t)i * 64 * K + 32);
    }
    b0 = *(const s16x8*)(Bp);
    b1 = *(const s16x8*)(Bp + 32);

    for (int k0 = 0; k0 < K; k0 += 64) {
        // ---- half A: consume stage0 (k0), prefetch k0+64 ----
        asm volatile("s_waitcnt lgkmcnt(0)" ::: "memory");
        __builtin_amdgcn_s_barrier();      // WAR: prev half's LDS reads done
        asm volatile("" ::: "memory");
        if (MERGEA) {
            s16x8 mv; M_COMBINE(mo0, ml0, mv);
            *(s16x8*)&As[arow][ac * 8] = mv;
        } else {
            #pragma unroll
            for (int i = 0; i < MI; ++i)
                *(s16x8*)&As[i * 64 + arow][ac * 8] = a0[i];
        }
        *(s16x8*)&Bs[arow][ac * 8] = b0;
        if (k0 + 64 < K) {
            if (MERGEA) M_ISSUE(k0 + 64, mo0, ml0);
            else {
                #pragma unroll
                for (int i = 0; i < MI; ++i)
                    a0[i] = *(const s16x8*)(Ap + (size_t)i * 64 * K + k0 + 64);
            }
            b0 = *(const s16x8*)(Bp + k0 + 64);
        }
        asm volatile("s_waitcnt lgkmcnt(0)" ::: "memory");
        __builtin_amdgcn_s_barrier();      // RAW: tile visible
        asm volatile("" ::: "memory");
        {
            s16x8 af[MI], bfr[4];
            #pragma unroll
            for (int i = 0; i < MI; ++i)
                af[i] = *(const s16x8*)&As[wid * (MI*16) + i * 16 + c][h * 8];
            #pragma unroll
            for (int j = 0; j < 4; ++j)
                bfr[j] = *(const s16x8*)&Bs[j * 16 + c][h * 8];
            #pragma unroll
            for (int i = 0; i < MI; ++i)
                #pragma unroll
                for (int j = 0; j < 4; ++j)
                    acc[i][j] = mfma16x16x32(af[i], bfr[j], acc[i][j]);
        }
        // ---- half B: consume stage1 (k0+32), prefetch k0+96 ----
        asm volatile("s_waitcnt lgkmcnt(0)" ::: "memory");
        __builtin_amdgcn_s_barrier();
        asm volatile("" ::: "memory");
        if (MERGEA) {
            s16x8 mv; M_COMBINE(mo1, ml1, mv);
            *(s16x8*)&As[arow][ac * 8] = mv;
        } else {
            #pragma unroll
            for (int i = 0; i < MI; ++i)
                *(s16x8*)&As[i * 64 + arow][ac * 8] = a1[i];
        }
        *(s16x8*)&Bs[arow][ac * 8] = b1;
        if (k0 + 96 < K) {
            if (MERGEA) M_ISSUE(k0 + 96, mo1, ml1);
            else {
                #pragma unroll
                for (int i = 0; i < MI; ++i)
                    a1[i] = *(const s16x8*)(Ap + (size_t)i * 64 * K + k0 + 96);
            }
            b1 = *(const s16x8*)(Bp + k0 + 96);
        }
        asm volatile("s_waitcnt lgkmcnt(0)" ::: "memory");
        __builtin_amdgcn_s_barrier();
        asm volatile("" ::: "memory");
        {
            s16x8 af[MI], bfr[4];
            #pragma unroll
            for (int i = 0; i < MI; ++i)
                af[i] = *(const s16x8*)&As[wid * (MI*16) + i * 16 + c][h * 8];
            #pragma unroll
            for (int j = 0; j < 4; ++j)
                bfr[j] = *(const s16x8*)&Bs[j * 16 + c][h * 8];
            #pragma unroll
            for (int i = 0; i < MI; ++i)
                #pragma unroll
                for (int j = 0; j < 4; ++j)
                    acc[i][j] = mfma16x16x32(af[i], bfr[j], acc[i][j]);
        }
    }
    #undef M_ISSUE
    #undef M_COMBINE

    float bj[4];
    #pragma unroll
    for (int j = 0; j < 4; ++j) bj[j] = bias[bx * 64 + j * 16 + c];
    #pragma unroll
    for (int i = 0; i < MI; ++i) {
        #pragma unroll
        for (int r = 0; r < 4; ++r) {
            int row = by * (MI*64) + wid * (MI*16) + i * 16 + h * 4 + r;
            #pragma unroll
            for (int j = 0; j < 4; ++j) {
                int col = bx * 64 + j * 16 + c;
                float v2 = acc[i][j][r] + bj[j];
                if (QSC && col < EE) v2 *= QSCALE;
                if (RES) v2 += res[(size_t)row * N + col];
                if (GELU_ACT) {
                    float u = 0.7978845608028654f * (v2 + 0.044715f * v2 * v2 * v2);
                    float t = exp2f(2.8853900817779268f * u);   // e^(2u)
                    v2 = v2 - v2 * __builtin_amdgcn_rcpf(t + 1.f); // v*t/(t+1)
                }
                if (OUT_BF) ((ushort_t*)C)[(size_t)row * N + col] = f2bf(v2);
                else        ((float*)C)[(size_t)row * N + col]    = v2;
            }
        }
    }
}

// ---------------------------------------------------------------------------
// Split-K causal flash attention (partial pass). 80 pieces/(b,h), 64-key
// tiles, reg-prefetch + lgkm-only barrier, max-free softmax, l via ones-MFMA,
// swapped-QK packed Ps writes, XCD-combo grouping.
// ROUND-26 (balanced split-K partition): the old t0=ks*8 partition gave
// maximally unbalanced pieces (qt=8 -> 8+1; qt=16 -> 8+8+1): the 8-tile
// pieces set the makespan while 1-tile pieces drain instantly (avg occupancy
// 33% despite 8-blocks/CU LDS headroom). Balanced: piece ks gets
// base+(ks<rem) tiles, base=(qt+1)/np, rem=(qt+1)%np -> qt=8: 5+4, qt=16:
// 6+6+5. The merge is partition-agnostic (sums np unnormalized partials),
// so only bf16 partial-sum grouping changes.
#define QB 64
#define KSTR 40
#define VSTR 88
#define PSTR 72
#define PTILES 8
__global__ __launch_bounds__(256) void attn_kernel(
    const ushort_t* __restrict__ qkv, ushort_t* __restrict__ o_part,
    float* __restrict__ l_part)
{
    __shared__ __align__(16) ushort_t Ks[QB][KSTR];
    __shared__ __align__(16) ushort_t Vt[DD][VSTR];
    __shared__ __align__(16) ushort_t Ps[4][16][PSTR];

    int tid  = threadIdx.x;
    // XCD-combo remap: flat -> (xcd, idx); xcd serves 4 (b,h) combos.
    int flat  = (blockIdx.z * HH + blockIdx.y) * 80 + blockIdx.x;
    int xcd   = flat & 7, idx = flat >> 3;        // idx 0..319
    int combo = xcd * 4 + (idx / 80);             // 0..31
    int piece = idx % 80;
    int p     = 79 - piece;                       // heavy (high qt) first
    int hh    = combo & 7, b = combo >> 3;
    int qt, ks;
    if (p < 8)       { qt = p;                 ks = 0; }
    else if (p < 24) { qt = 8  + ((p-8)  >> 1); ks = (p-8)  & 1; }
    else if (p < 48) { qt = 16 + (p-24) / 3;    ks = (p-24) % 3; }
    else             { qt = 24 + ((p-48) >> 2); ks = (p-48) & 3; }
    int wid  = tid >> 6, lane = tid & 63;
    int h    = lane >> 4, c = lane & 15;

    int qfrow = qt * QB + wid * 16 + c;
    s16x8 qfrag = *(const s16x8*)(qkv + ((size_t)(b * SS + qfrow)) * (3*EE)
                                  + hh * DD + h * 8);

    s16x8 onesf = { (short)0x3F80, (short)0x3F80, (short)0x3F80, (short)0x3F80,
                    (short)0x3F80, (short)0x3F80, (short)0x3F80, (short)0x3F80 };

    f32x4 o0 = {0.f,0.f,0.f,0.f}, o1 = {0.f,0.f,0.f,0.f}, o2 = {0.f,0.f,0.f,0.f};

    int srow = tid >> 2, scq = tid & 3;

    // balanced partition of nt=qt+1 tiles over np=(qt>>3)+1 pieces
    int np   = (qt >> 3) + 1;
    int nt   = qt + 1;
    int base = nt / np, rem = nt % np;
    int t0   = ks * base + min(ks, rem);
    int t1   = t0 + base + (ks < rem ? 1 : 0);

    s16x8 kreg, vreg;
    {
        const ushort_t* kb = qkv + ((size_t)(b * SS + t0 * QB)) * (3*EE) + hh * DD + EE;
        kreg = *(const s16x8*)(kb + (size_t)srow * (3*EE) + scq * 8);
        vreg = *(const s16x8*)(kb + EE + (size_t)srow * (3*EE) + scq * 8);
    }

    for (int kt = t0; kt < t1; ++kt) {
        int k0 = kt * QB;

        __syncthreads();   // prev tile's LDS reads done

        *(s16x8*)&Ks[srow][scq * 8] = kreg;
        {
            int d0 = scq * 8;
            int colw = srow ^ (scq << 4);          // XOR swizzle
            #pragma unroll
            for (int j = 0; j < 8; ++j) Vt[d0 + j][colw] = (ushort_t)vreg[j];
        }
        if (kt + 1 < t1) {
            const ushort_t* kb2 = qkv + ((size_t)(b * SS + (kt+1) * QB)) * (3*EE)
                                  + hh * DD + EE;
            kreg = *(const s16x8*)(kb2 + (size_t)srow * (3*EE) + scq * 8);
            vreg = *(const s16x8*)(kb2 + EE + (size_t)srow * (3*EE) + scq * 8);
        }

        asm volatile("s_waitcnt lgkmcnt(0)" ::: "memory");
        __builtin_amdgcn_s_barrier();
        asm volatile("" ::: "memory");

        __builtin_amdgcn_s_setprio(1);

        // QK (swapped): lane holds S[q=c][key = g*16 + h*4 + r]
        f32x4 sg[4];
        #pragma unroll
        for (int g = 0; g < 4; ++g) {
            s16x8 kf = *(const s16x8*)&Ks[g * 16 + c][h * 8];
            f32x4 z = {0.f,0.f,0.f,0.f};
            sg[g] = mfma16x16x32(kf, qfrag, z);
        }

        if (kt == qt) {                       // diagonal tile: masked path
            int klim = qfrow - k0;
            #pragma unroll
            for (int g = 0; g < 4; ++g) {
                ushort4 pk;
                #pragma unroll
                for (int r = 0; r < 4; ++r) {
                    float x = sg[g][r];
                    if (g * 16 + h * 4 + r > klim) x = -INFINITY;
                    ((ushort_t*)&pk)[r] = f2bf(exp2f(x));
                }
                *(ushort4*)&Ps[wid][c][g * 16 + h * 4] = pk;
            }
        } else {                              // interior tile: no masking
            #pragma unroll
            for (int g = 0; g < 4; ++g) {
                ushort4 pk;
                #pragma unroll
                for (int r = 0; r < 4; ++r)
                    ((ushort_t*)&pk)[r] = f2bf(exp2f(sg[g][r]));
                *(ushort4*)&Ps[wid][c][g * 16 + h * 4] = pk;
            }
        }

        #pragma unroll
        for (int kc = 0; kc < 2; ++kc) {
            int kbase = kc * 32 + h * 8;
            s16x8 pf = *(const s16x8*)&Ps[wid][c][kbase];
            s16x8 v0 = *(const s16x8*)&Vt[c]     [kbase ^ ((c >> 3) << 4)];
            s16x8 v1 = *(const s16x8*)&Vt[16 + c][kbase ^ (((16 + c) >> 3) << 4)];
            o0 = mfma16x16x32(pf, v0, o0);
            o1 = mfma16x16x32(pf, v1, o1);
            o2 = mfma16x16x32(pf, onesf, o2);   // row sums -> l
        }

        __builtin_amdgcn_s_setprio(0);
    }

    // write partials for ALL rows (merge fused into proj GEMM)
    size_t rbase = (size_t)(b * HH + hh) * SS;
    #pragma unroll
    for (int r = 0; r < 4; ++r) {
        int qrow = qt * QB + wid * 16 + h * 4 + r;
        size_t rl = rbase + qrow;
        ushort_t* op = o_part + ((size_t)ks * NRL + rl) * DD;
        op[c]      = f2bf(o0[r]);
        op[16 + c] = f2bf(o1[r]);
        if (c == 0) l_part[(size_t)ks * NRL + rl] = o2[r];
    }
}

// ---------------------------------------------------------------------------
extern "C" void kernel_launch(void* const* d_in, const int* in_sizes, int n_in,
                              void* d_out, int out_size, void* d_ws, size_t ws_size,
                              hipStream_t stream)
{
    const int*   ids    = (const int*)  d_in[0];
    const float* wte    = (const float*)d_in[1];
    const float* wpe    = (const float*)d_in[2];
    const float* ln1_g  = (const float*)d_in[3];
    const float* ln1_b  = (const float*)d_in[4];
    const float* qkv_w  = (const float*)d_in[5];
    const float* qkv_b  = (const float*)d_in[6];
    const float* proj_w = (const float*)d_in[7];
    const float* proj_b = (const float*)d_in[8];
    const float* ln2_g  = (const float*)d_in[9];
    const float* ln2_b  = (const float*)d_in[10];
    const float* fc1_w  = (const float*)d_in[11];
    const float* fc1_b  = (const float*)d_in[12];
    const float* fc2_w  = (const float*)d_in[13];
    const float* fc2_b  = (const float*)d_in[14];
    const float* lnf_g  = (const float*)d_in[15];
    const float* lnf_b  = (const float*)d_in[16];

    float*    h        = (float*)d_ws;                         // 8192*256 f32
    ushort_t* x_bf     = (ushort_t*)(h + (size_t)NROWS*EE);    // 8192*256
    ushort_t* qkv_bf   = x_bf   + (size_t)NROWS*EE;            // 8192*768
    ushort_t* attno_bf = qkv_bf + (size_t)NROWS*3*EE;          // 8192*256 (spare)
    ushort_t* m1_bf    = attno_bf + (size_t)NROWS*EE;          // 8192*1024
    ushort_t* wq_t     = m1_bf  + (size_t)NROWS*NI;            // [2][768][256]
    ushort_t* wp_t     = wq_t   + (size_t)2*3*EE*EE;           // [2][256][256]
    ushort_t* w1_t     = wp_t   + (size_t)2*EE*EE;             // [2][1024][256]
    ushort_t* w2_t     = w1_t   + (size_t)2*EE*NI;             // [2][256][1024]

    // split-K scratch overlays (regions dead during attention + proj):
    ushort_t* o_part   = m1_bf;              // 4*65536*32*2B = 16.78MB == m1 region
    float*    l_part   = (float*)x_bf;       // 4*65536*4B    = 1.05MB  <  x region

    wconv_all<<<dim3(768, LL), 256, 0, stream>>>(
        qkv_w, proj_w, fc1_w, fc2_w, wq_t, wp_t, w1_t, w2_t);

    embed_ln_kernel<<<NROWS/4, 256, 0, stream>>>(ids, wte, wpe, ln1_g, ln1_b, h, x_bf);

    for (int l = 0; l < LL; ++l) {
        if (l > 0)
            ln_kernel<true><<<NROWS/4, 256, 0, stream>>>(h, ln1_g + l*EE, ln1_b + l*EE, x_bf);
        gemm_bf<2,true,false,false,true,false><<<dim3(3*EE/64, NROWS/128), 256, 0, stream>>>(
            x_bf, wq_t + (size_t)l*3*EE*EE, qkv_b + (size_t)l*3*EE, nullptr,
            qkv_bf, nullptr, NROWS, 3*EE, EE);
        attn_kernel<<<dim3(80, HH, BB), 256, 0, stream>>>(qkv_bf, o_part, l_part);
        // proj GEMM with fused split-K merge (A = o_part + l_part)
        gemm_bf<1,false,false,true,false,true><<<dim3(EE/64, NROWS/64), 256, 0, stream>>>(
            o_part, wp_t + (size_t)l*EE*EE, proj_b + (size_t)l*EE, h,
            h, l_part, NROWS, EE, EE);
        ln_kernel<true><<<NROWS/4, 256, 0, stream>>>(h, ln2_g + l*EE, ln2_b + l*EE, x_bf);
        gemm_bf<2,true,true,false,false,false><<<dim3(NI/64, NROWS/128), 256, 0, stream>>>(
            x_bf, w1_t + (size_t)l*EE*NI, fc1_b + (size_t)l*NI, nullptr,
            m1_bf, nullptr, NROWS, NI, EE);
        gemm_bf<1,false,false,true,false,false><<<dim3(EE/64, NROWS/64), 256, 0, stream>>>(
            m1_bf, w2_t + (size_t)l*NI*EE, fc2_b + (size_t)l*EE, h,
            h, nullptr, NROWS, EE, NI);
    }

    ln_kernel<false><<<NROWS/4, 256, 0, stream>>>(h, lnf_g, lnf_b, (float*)d_out);
}